// Round 16
// baseline (737.449 us; speedup 1.0000x reference)
//
#include <hip/hip_runtime.h>
#include <stdint.h>

// Problem constants
#define B_     2
#define T_     4096
#define NB_    4
#define D_     512
#define E_     4096
#define NE_    16384           // NB*E
#define HALF_  67108864u       // T*NB*E  (per-b flat block of [B,T,NB,E])
#define SLOTS_ 32768           // B*T*NB
#define XN8_   2097152         // B*T*NB*D/8
#define WN8_   1048576         // NB*E*D/8
#define MT_    32              // m-tiles per b = T/128
#define RECN_  (64 * NE_)      // (MT_*B) * NE records per key array

typedef unsigned long long u64;
typedef uint32_t u32;
typedef uint16_t u16;
typedef _Float16 f16x8 __attribute__((ext_vector_type(8)));
typedef float    f32x4 __attribute__((ext_vector_type(4)));

// ---------------- Threefry-2x32-20, key = (0, 42) ----------------
__device__ __forceinline__ u32 rotl32(u32 x, int r) { return __builtin_rotateleft32(x, r); }

__device__ __forceinline__ void tf_0_42(u32 x0, u32 x1, u32 &o0, u32 &o1) {
  const u32 ks0 = 0u, ks1 = 42u, ks2 = 0x1BD11BDAu ^ 0u ^ 42u;
  x0 += ks0; x1 += ks1;
#define TFR(r) { x0 += x1; x1 = rotl32(x1, (r)); x1 ^= x0; }
  TFR(13) TFR(15) TFR(26) TFR(6)
  x0 += ks1; x1 += ks2 + 1u;
  TFR(17) TFR(29) TFR(16) TFR(24)
  x0 += ks2; x1 += ks0 + 2u;
  TFR(13) TFR(15) TFR(26) TFR(6)
  x0 += ks0; x1 += ks1 + 3u;
  TFR(17) TFR(29) TFR(16) TFR(24)
  x0 += ks1; x1 += ks2 + 4u;
  TFR(13) TFR(15) TFR(26) TFR(6)
  x0 += ks2; x1 += ks0 + 5u;
#undef TFR
  o0 = x0; o1 = x1;
}

// Partitionable noise (VERIFIED R7): XOR fold o0^o1 of threefry(key,(0,i))
__device__ __forceinline__ float noise_at(u32 i) {
  u32 o0, o1; tf_0_42(0u, i, o0, o1);
  u32 bits = o0 ^ o1;
  float f = __uint_as_float((bits >> 9) | 0x3F800000u);  // [1,2)
  return 2.0f - f;                                        // 1 - uniform
}

// order-preserving map fp32 -> u32, branchless (finite inputs)
__device__ __forceinline__ u32 map_f32(float v) {
  u32 u = __float_as_uint(v);
  u32 s = (u32)((int)u >> 31);               // 0 or 0xFFFFFFFF
  return u ^ (s | 0x80000000u);
}

// merge two sorted-desc key triples: (a0>=a1>=a2) <- top3 of {a*, b*}
__device__ __forceinline__ void merge3(u64 &a0, u64 &a1, u64 &a2,
                                       u64 b0, u64 b1, u64 b2) {
  u64 o0, o1, o2;
  if (a0 >= b0) {
    o0 = a0;
    if (a1 >= b0) { o1 = a1; o2 = (a2 >= b0) ? a2 : b0; }
    else          { o1 = b0; o2 = (a1 >= b1) ? a1 : b1; }
  } else {
    o0 = b0;
    if (b1 >= a0) { o1 = b1; o2 = (b2 >= a0) ? b2 : a0; }
    else          { o1 = a0; o2 = (b1 >= a1) ? b1 : a1; }
  }
  a0 = o0; a1 = o1; a2 = o2;
}

#define BASE_KEY 0x80000000FFFFFFFFull   // (+0.0, e=0): empty slot -> argmax 0
#define SCALE_   2048.0f
#define INV_SC   (1.0f / 4194304.0f)     // 2^-22

// ---------------- Kernel 1: init keys + prune thresholds ----------------
__global__ __launch_bounds__(256) void init_keys(u64* __restrict__ keys,
                                                 u32* __restrict__ thr) {
  int i = blockIdx.x * 256 + threadIdx.x;    // 32768
  keys[i] = BASE_KEY;
  thr[i]  = 0u;
}

// ---------------- Kernel 1b: pre-split fp32 -> (hi,lo) fp16, scaled by 2^11 ----------------
__device__ __forceinline__ void split8v(const float4 a0, const float4 a1, f16x8 &hi, f16x8 &lo) {
  float fv[8] = {a0.x, a0.y, a0.z, a0.w, a1.x, a1.y, a1.z, a1.w};
#pragma unroll
  for (int j = 0; j < 8; ++j) {
    float f = fv[j] * SCALE_;
    _Float16 h = (_Float16)f;
    hi[j] = h;
    lo[j] = (_Float16)(f - (float)h);
  }
}

__global__ __launch_bounds__(256) void presplit(const float* __restrict__ x,
                                                const float* __restrict__ W,
                                                f16x8* __restrict__ xh, f16x8* __restrict__ xl,
                                                f16x8* __restrict__ wh, f16x8* __restrict__ wl) {
  size_t g = (size_t)blockIdx.x * 256 + threadIdx.x;   // unit = 8 floats
  const float4* src;
  f16x8 *dh, *dl;
  size_t off;
  if (g < XN8_) { src = (const float4*)x; dh = xh; dl = xl; off = g; }
  else          { src = (const float4*)W; dh = wh; dl = wl; off = g - XN8_; }
  float4 a0 = src[off * 2], a1 = src[off * 2 + 1];
  f16x8 hi, lo;
  split8v(a0, a1, hi, lo);
  dh[off] = hi; dl[off] = lo;
}

// ---------------- Kernel 2: fused GEMM + compacted pruned noisy top-3 select ----------------
#define BM 128
#define BN 128

__global__ __launch_bounds__(256) void gemm_fused(const f16x8* __restrict__ xh,
                                                  const f16x8* __restrict__ xl,
                                                  const f16x8* __restrict__ wh,
                                                  const f16x8* __restrict__ wl,
                                                  float* __restrict__ logits,
                                                  u64* __restrict__ k0g,
                                                  u64* __restrict__ k1g,
                                                  u64* __restrict__ k2g,
                                                  u32* __restrict__ thrbuf) {
  __shared__ f16x8 lds_raw[2048];            // 32 KB, repurposed across phases
  f16x8* AhV = lds_raw;                      // K-loop layout
  f16x8* AlV = lds_raw + 512;
  f16x8* BhV = lds_raw + 1024;
  f16x8* BlV = lds_raw + 1536;

  // XCD-chunked swizzle (R16): physical blocks round-robin across 8 XCDs;
  // remap so each XCD owns 1024 CONSECUTIVE logical ids -> the 32 blocks
  // sharing an A-tile run on one XCD (A fetched once per XCD, not 8x).
  // Bijective: 8192 % 8 == 0.  Pure permutation -> outputs unchanged.
  const int phys = blockIdx.x;
  const int id   = (phys & 7) * 1024 + (phys >> 3);
  const int e0 = (id & 31) * BN;
  const int n  = (id >> 5) & 3;
  const int mt = id >> 7;                    // 0..63
  const int m0 = mt * BM;                    // m = b*T + t

  const int tid  = threadIdx.x;
  const int lane = tid & 63;
  const int wid  = tid >> 6;                 // 4 waves: wid = wr*2 + wc
  const int wr   = wid >> 1;
  const int wc   = wid & 1;
  const int lm   = lane & 15;
  const int lk   = lane >> 4;                // k-group 0..3

  f32x4 acc[4][4];
#pragma unroll
  for (int i = 0; i < 4; ++i)
#pragma unroll
    for (int j = 0; j < 4; ++j) acc[i][j] = (f32x4){0.f, 0.f, 0.f, 0.f};

  for (int k0 = 0; k0 < D_ / 8; k0 += 4) {   // K-step = 32 halfs = 4 groups
#pragma unroll
    for (int l = 0; l < 2; ++l) {
      int aid = tid + l * 256;               // 0..511
      int r   = aid >> 2;                    // 0..127 (tile row)
      int ko  = aid & 3;                     // k-group
      int ps  = ko ^ ((r >> 1) & 3);         // swizzled slot
      size_t gA = ((size_t)(m0 + r) * NB_ + n) * (D_ / 8) + k0 + ko;
      AhV[r * 4 + ps] = xh[gA];
      AlV[r * 4 + ps] = xl[gA];
      size_t gB = ((size_t)n * E_ + e0 + r) * (D_ / 8) + k0 + ko;
      BhV[r * 4 + ps] = wh[gB];
      BlV[r * 4 + ps] = wl[gB];
    }
    __syncthreads();

    f16x8 bh[4], bl[4];
#pragma unroll
    for (int fn = 0; fn < 4; ++fn) {
      int row = wc * 64 + fn * 16 + lm;
      int ps  = lk ^ ((row >> 1) & 3);
      bh[fn] = BhV[row * 4 + ps];
      bl[fn] = BlV[row * 4 + ps];
    }
#pragma unroll
    for (int fm = 0; fm < 4; ++fm) {
      int row = wr * 64 + fm * 16 + lm;
      int ps  = lk ^ ((row >> 1) & 3);
      f16x8 ah = AhV[row * 4 + ps];
      f16x8 al = AlV[row * 4 + ps];
#pragma unroll
      for (int fn = 0; fn < 4; ++fn) {
        acc[fm][fn] = __builtin_amdgcn_mfma_f32_16x16x32_f16(ah, bh[fn], acc[fm][fn], 0, 0, 0);
        acc[fm][fn] = __builtin_amdgcn_mfma_f32_16x16x32_f16(ah, bl[fn], acc[fm][fn], 0, 0, 0);
        acc[fm][fn] = __builtin_amdgcn_mfma_f32_16x16x32_f16(al, bh[fn], acc[fm][fn], 0, 0, 0);
      }
    }
    __syncthreads();
  }
  // After the final barrier all K-loop LDS reads are done -> repurpose LDS:
  float* lgbuf = (float*)lds_raw;                    // 16 KB: [16 slots][256 threads]
  u16*   tbuf  = (u16*)((char*)lds_raw + 16384);     //  8 KB: [16 slots][256 threads]
  u64*   ldsK  = (u64*)((char*)lds_raw + 24576);     //  6 KB: [4 waves][64 cols][3]

  // ---- epilogue part 1: store logits ----
  const int b     = m0 >> 12;                // m0 / T_
  const int mbase = m0 & (T_ - 1);           // t of tile row 0
  const int mtile = mbase >> 7;

#pragma unroll
  for (int fm = 0; fm < 4; ++fm) {
#pragma unroll
    for (int r = 0; r < 4; ++r) {
      int m = m0 + wr * 64 + fm * 16 + lk * 4 + r;
      float* row = logits + ((size_t)m * NB_ + n) * E_ + e0 + wc * 64 + lm;
#pragma unroll
      for (int fn = 0; fn < 4; ++fn) row[fn * 16] = acc[fm][fn][r] * INV_SC;
    }
  }

  // ---- epilogue part 2: compacted pruned per-column noisy top-3 ----
  // Gate (exact): y <= ub = max(lg,0); skip iff map(ub) < thr (thr = subset 3rd-max,
  // monotone via atomicMax; stale reads only reduce pruning, never wrongness).
#pragma unroll
  for (int fn = 0; fn < 4; ++fn) {
    const int e  = e0 + wc * 64 + fn * 16 + lm;   // e within [0,E)
    const int ne = n * E_ + e;
    const u32 thrv = thrbuf[(size_t)b * NE_ + ne];

    // pass 1: compact candidates (lg, t) into LDS
    int cnt = 0;
#pragma unroll
    for (int fm = 0; fm < 4; ++fm) {              // t ascends per lane
#pragma unroll
      for (int r = 0; r < 4; ++r) {
        float lg = acc[fm][fn][r] * INV_SC;
        u32 mu = __float_as_uint(fmaxf(lg, 0.0f)) | 0x80000000u;   // map(ub)
        if (mu >= thrv) {
          lgbuf[cnt * 256 + tid] = lg;
          tbuf [cnt * 256 + tid] = (u16)(mbase + wr * 64 + fm * 16 + lk * 4 + r);
          ++cnt;
        }
      }
    }

    // pass 2: evaluate candidates (wave runs max(cnt) iterations)
    u32 v0 = 0, v1 = 0, v2 = 0;
    u32 tt0 = 0, tt1 = 0, tt2 = 0;
    const u32 ibase = (u32)b * HALF_ + (u32)ne;
    for (int k = 0; k < cnt; ++k) {
      float lg = lgbuf[k * 256 + tid];
      u32 t    = (u32)tbuf[k * 256 + tid];
      float y  = lg * noise_at(ibase + t * (u32)NE_);
      u32 mv = map_f32(y);
      bool g0 = mv > v0, g1 = mv > v1, g2 = mv > v2;
      v2  = g1 ? v1  : (g2 ? mv : v2);
      tt2 = g1 ? tt1 : (g2 ? t  : tt2);
      v1  = g0 ? v0  : (g1 ? mv : v1);
      tt1 = g0 ? tt0 : (g1 ? t  : tt1);
      v0  = g0 ? mv  : v0;
      tt0 = g0 ? t   : tt0;
    }

    u64 K0 = ((u64)v0 << 32) | (u64)(0xFFFFFFFFu - tt0);
    u64 K1 = ((u64)v1 << 32) | (u64)(0xFFFFFFFFu - tt1);
    u64 K2 = ((u64)v2 << 32) | (u64)(0xFFFFFFFFu - tt2);
    // merge across the 4 lk-lanes of this lm-group
    u64 p0 = __shfl_xor(K0, 16), p1 = __shfl_xor(K1, 16), p2 = __shfl_xor(K2, 16);
    merge3(K0, K1, K2, p0, p1, p2);
    p0 = __shfl_xor(K0, 32); p1 = __shfl_xor(K1, 32); p2 = __shfl_xor(K2, 32);
    merge3(K0, K1, K2, p0, p1, p2);
    if (lk == 0) {
      int c = fn * 16 + lm;                  // 0..63
      ldsK[(wid * 64 + c) * 3 + 0] = K0;
      ldsK[(wid * 64 + c) * 3 + 1] = K1;
      ldsK[(wid * 64 + c) * 3 + 2] = K2;
    }
  }
  __syncthreads();
  if (wid < 2) {                             // wr==0 waves merge with their wr==1 partner
    int c = lane;                            // 0..63; e = e0 + wid*64 + c  (wid == wc here)
    u64 A0 = ldsK[(wid * 64 + c) * 3 + 0];
    u64 A1 = ldsK[(wid * 64 + c) * 3 + 1];
    u64 A2 = ldsK[(wid * 64 + c) * 3 + 2];
    u64 C0 = ldsK[((wid + 2) * 64 + c) * 3 + 0];
    u64 C1 = ldsK[((wid + 2) * 64 + c) * 3 + 1];
    u64 C2 = ldsK[((wid + 2) * 64 + c) * 3 + 2];
    merge3(A0, A1, A2, C0, C1, C2);
    int eg = e0 + wid * 64 + c;
    size_t R = (size_t)(mtile * 2 + b) * NE_ + (size_t)n * E_ + eg;
    k0g[R] = A0; k1g[R] = A1; k2g[R] = A2;
    // publish this tile's evaluated-subset 3rd-max as a prune threshold
    atomicMax(&thrbuf[(size_t)b * NE_ + (size_t)n * E_ + eg], (u32)(A2 >> 32));
  }
}

// ---------------- Kernel 3: merge tile records -> global top-3 -> slot scatter ----------------
__global__ __launch_bounds__(256) void merge_scatter2(const u64* __restrict__ k0g,
                                                      const u64* __restrict__ k1g,
                                                      const u64* __restrict__ k2g,
                                                      u64* __restrict__ keys) {
  int gid2 = blockIdx.x * 256 + threadIdx.x;  // 32768 = B*NB*E
  int b  = gid2 >> 14;
  int ne = gid2 & (NE_ - 1);

  u64 K0 = 0, K1 = 0, K2 = 0;
  for (int mt = 0; mt < MT_; ++mt) {
    size_t R = (size_t)(mt * 2 + b) * NE_ + ne;
    merge3(K0, K1, K2, k0g[R], k1g[R], k2g[R]);
  }

  int n = ne >> 12;
  u32 e = (u32)(ne & (E_ - 1));
  u64 elo = (u64)(0xFFFFFFFFu - e);
  u32 t0 = 0xFFFFFFFFu - (u32)K0;
  u32 t1 = 0xFFFFFFFFu - (u32)K1;
  u32 t2 = 0xFFFFFFFFu - (u32)K2;
  atomicMax(&keys[((size_t)b * T_ + t0) * NB_ + n], (K0 & 0xFFFFFFFF00000000ull) | elo);
  atomicMax(&keys[((size_t)b * T_ + t1) * NB_ + n], (K1 & 0xFFFFFFFF00000000ull) | elo);
  atomicMax(&keys[((size_t)b * T_ + t2) * NB_ + n], (K2 & 0xFFFFFFFF00000000ull) | elo);
}

// ---------------- Fallback path (small ws): in-kernel-split GEMM + monolithic select ----------------
__device__ __forceinline__ void split8(const float* __restrict__ p, f16x8 &hi, f16x8 &lo) {
  float4 a0 = *(const float4*)p;
  float4 a1 = *(const float4*)(p + 4);
  split8v(a0, a1, hi, lo);
}

__global__ __launch_bounds__(256) void gemm_logits_fb(const float* __restrict__ x,
                                                      const float* __restrict__ W,
                                                      float* __restrict__ logits) {
  __shared__ f16x8 AhV[128 * 4];
  __shared__ f16x8 AlV[128 * 4];
  __shared__ f16x8 BhV[128 * 4];
  __shared__ f16x8 BlV[128 * 4];

  const int n  = blockIdx.z;
  const int m0 = blockIdx.y * BM;
  const int e0 = blockIdx.x * BN;
  const int tid  = threadIdx.x;
  const int lane = tid & 63;
  const int wid  = tid >> 6;
  const int wr   = wid >> 1;
  const int wc   = wid & 1;
  const int lm   = lane & 15;
  const int lk   = lane >> 4;

  const float* Abase = x + ((size_t)m0 * NB_ + n) * D_;
  const float* Bbase = W + ((size_t)n * E_ + e0) * D_;

  f32x4 acc[4][4];
#pragma unroll
  for (int i = 0; i < 4; ++i)
#pragma unroll
    for (int j = 0; j < 4; ++j) acc[i][j] = (f32x4){0.f, 0.f, 0.f, 0.f};

  for (int k0 = 0; k0 < D_; k0 += 32) {
#pragma unroll
    for (int l = 0; l < 2; ++l) {
      int aid = tid + l * 256;
      int r   = aid >> 2;
      int ko  = aid & 3;
      int ps  = ko ^ ((r >> 1) & 3);
      f16x8 hi, lo;
      split8(Abase + (size_t)r * (NB_ * D_) + k0 + ko * 8, hi, lo);
      AhV[r * 4 + ps] = hi; AlV[r * 4 + ps] = lo;
      split8(Bbase + (size_t)r * D_ + k0 + ko * 8, hi, lo);
      BhV[r * 4 + ps] = hi; BlV[r * 4 + ps] = lo;
    }
    __syncthreads();

    f16x8 bh[4], bl[4];
#pragma unroll
    for (int fn = 0; fn < 4; ++fn) {
      int row = wc * 64 + fn * 16 + lm;
      int ps  = lk ^ ((row >> 1) & 3);
      bh[fn] = BhV[row * 4 + ps];
      bl[fn] = BlV[row * 4 + ps];
    }
#pragma unroll
    for (int fm = 0; fm < 4; ++fm) {
      int row = wr * 64 + fm * 16 + lm;
      int ps  = lk ^ ((row >> 1) & 3);
      f16x8 ah = AhV[row * 4 + ps];
      f16x8 al = AlV[row * 4 + ps];
#pragma unroll
      for (int fn = 0; fn < 4; ++fn) {
        acc[fm][fn] = __builtin_amdgcn_mfma_f32_16x16x32_f16(ah, bh[fn], acc[fm][fn], 0, 0, 0);
        acc[fm][fn] = __builtin_amdgcn_mfma_f32_16x16x32_f16(ah, bl[fn], acc[fm][fn], 0, 0, 0);
        acc[fm][fn] = __builtin_amdgcn_mfma_f32_16x16x32_f16(al, bh[fn], acc[fm][fn], 0, 0, 0);
      }
    }
    __syncthreads();
  }

#pragma unroll
  for (int fm = 0; fm < 4; ++fm) {
#pragma unroll
    for (int fn = 0; fn < 4; ++fn) {
#pragma unroll
      for (int r = 0; r < 4; ++r) {
        int m = m0 + wr * 64 + fm * 16 + lk * 4 + r;
        int e = e0 + wc * 64 + fn * 16 + lm;
        logits[((size_t)m * NB_ + n) * E_ + e] = acc[fm][fn][r] * INV_SC;
      }
    }
  }
}

__global__ __launch_bounds__(256) void select_scatter(const float* __restrict__ logits,
                                                      u64* __restrict__ keys) {
  int gid = blockIdx.x * 256 + threadIdx.x;  // 32768 = B*NB*E
  int b  = gid >> 14;
  int ne = gid & (NE_ - 1);

  float v0 = -1e30f, v1 = -1e30f, v2 = -1e30f;
  int   t0 = 0, t1 = 0, t2 = 0;

  const float* lg = logits + (size_t)b * HALF_;
  const u32 ib = (u32)b * HALF_ + (u32)ne;
  for (int t = 0; t < T_; ++t) {
    u32 i0 = (u32)t * (u32)NE_ + (u32)ne;
    float y = lg[i0] * noise_at(ib + (u32)t * (u32)NE_);
    if (y > v0)      { v2=v1; t2=t1; v1=v0; t1=t0; v0=y; t0=t; }
    else if (y > v1) { v2=v1; t2=t1; v1=y;  t1=t; }
    else if (y > v2) { v2=y;  t2=t; }
  }

  int n = ne >> 12;
  int e = ne & (E_ - 1);
  u64 klo = 0xFFFFFFFFull - (u32)e;
  atomicMax(&keys[((size_t)b * T_ + t0) * NB_ + n], ((u64)map_f32(v0) << 32) | klo);
  atomicMax(&keys[((size_t)b * T_ + t1) * NB_ + n], ((u64)map_f32(v1) << 32) | klo);
  atomicMax(&keys[((size_t)b * T_ + t2) * NB_ + n], ((u64)map_f32(v2) << 32) | klo);
}

// ---------------- Kernel 4: decode argmax -> idx + latent gather ----------------
__global__ __launch_bounds__(128) void finalize(const u64* __restrict__ keys,
                                                const float* __restrict__ W,
                                                float* __restrict__ out_idx,
                                                float* __restrict__ out_lat) {
  int slot = blockIdx.x;                     // (b*T+t)*NB + n
  int n = slot & (NB_ - 1);
  int e = (int)(0xFFFFFFFFu - (u32)keys[slot]) & (E_ - 1);
  if (threadIdx.x == 0) out_idx[slot] = (float)e;

  const float4 v = ((const float4*)(W + ((size_t)n * E_ + e) * D_))[threadIdx.x];
  ((float4*)(out_lat + (size_t)slot * D_))[threadIdx.x] = v;   // 128 x 16B = 2KB
}

// ---------------- Launch ----------------
extern "C" void kernel_launch(void* const* d_in, const int* in_sizes, int n_in,
                              void* d_out, int out_size, void* d_ws, size_t ws_size,
                              hipStream_t stream) {
  const float* x = (const float*)d_in[0];    // [B,T,NB*D] fp32
  const float* W = (const float*)d_in[1];    // [NB,E,D]  fp32

  float* out_idx    = (float*)d_out;                          // 32,768
  float* out_lat    = out_idx + (size_t)SLOTS_;               // 16,777,216
  float* out_logits = out_lat + (size_t)SLOTS_ * D_;          // 134,217,728

  // ws layout: keys | thr | xh | xl | wh | wl
  u64* keys = (u64*)d_ws;
  const size_t KEYS_B = (size_t)SLOTS_ * 8;                   // 256 KiB
  const size_t THR_B  = (size_t)SLOTS_ * 4;                   // 128 KiB
  const size_t XH_B   = (size_t)XN8_ * 16;                    // 32 MiB
  const size_t WH_B   = (size_t)WN8_ * 16;                    // 16 MiB
  bool split = ws_size >= KEYS_B + THR_B + 2 * XH_B + 2 * WH_B;

  u32*   thr = (u32*)((char*)d_ws + KEYS_B);
  char*  sp  = (char*)d_ws + KEYS_B + THR_B;
  f16x8* xh  = (f16x8*)sp;
  f16x8* xl  = (f16x8*)(sp + XH_B);
  f16x8* wh  = (f16x8*)(sp + 2 * XH_B);
  f16x8* wl  = (f16x8*)(sp + 2 * XH_B + WH_B);

  // tile-select records live in the out_lat region (overwritten by finalize later)
  u64* k0g = (u64*)out_lat;                                   // 8 MB each
  u64* k1g = k0g + RECN_;
  u64* k2g = k1g + RECN_;

  init_keys<<<SLOTS_ / 256, 256, 0, stream>>>(keys, thr);

  if (split) {
    presplit<<<(XN8_ + WN8_) / 256, 256, 0, stream>>>(x, W, xh, xl, wh, wl);
    gemm_fused<<<8192, 256, 0, stream>>>(xh, xl, wh, wl, out_logits, k0g, k1g, k2g, thr);
    merge_scatter2<<<SLOTS_ / 256, 256, 0, stream>>>(k0g, k1g, k2g, keys);
  } else {
    dim3 ggrid(E_ / BN, (B_ * T_) / BM, NB_);
    gemm_logits_fb<<<ggrid, 256, 0, stream>>>(x, W, out_logits);
    select_scatter<<<SLOTS_ / 256, 256, 0, stream>>>(out_logits, keys);
  }

  finalize<<<SLOTS_, 128, 0, stream>>>(keys, W, out_idx, out_lat);
}

// Round 17
// 710.090 us; speedup vs baseline: 1.0385x; 1.0385x over previous
//
#include <hip/hip_runtime.h>
#include <stdint.h>

// Problem constants
#define B_     2
#define T_     4096
#define NB_    4
#define D_     512
#define E_     4096
#define NE_    16384           // NB*E
#define HALF_  67108864u       // T*NB*E  (per-b flat block of [B,T,NB,E])
#define SLOTS_ 32768           // B*T*NB
#define XN8_   2097152         // B*T*NB*D/8
#define WN8_   1048576         // NB*E*D/8
#define MT_    32              // m-tiles per b = T/128
#define RECN_  (64 * NE_)      // (MT_*B) * NE records per key array

typedef unsigned long long u64;
typedef uint32_t u32;
typedef uint16_t u16;
typedef _Float16 f16x8 __attribute__((ext_vector_type(8)));
typedef float    f32x4 __attribute__((ext_vector_type(4)));

// ---------------- Threefry-2x32-20, key = (0, 42) ----------------
__device__ __forceinline__ u32 rotl32(u32 x, int r) { return __builtin_rotateleft32(x, r); }

__device__ __forceinline__ void tf_0_42(u32 x0, u32 x1, u32 &o0, u32 &o1) {
  const u32 ks0 = 0u, ks1 = 42u, ks2 = 0x1BD11BDAu ^ 0u ^ 42u;
  x0 += ks0; x1 += ks1;
#define TFR(r) { x0 += x1; x1 = rotl32(x1, (r)); x1 ^= x0; }
  TFR(13) TFR(15) TFR(26) TFR(6)
  x0 += ks1; x1 += ks2 + 1u;
  TFR(17) TFR(29) TFR(16) TFR(24)
  x0 += ks2; x1 += ks0 + 2u;
  TFR(13) TFR(15) TFR(26) TFR(6)
  x0 += ks0; x1 += ks1 + 3u;
  TFR(17) TFR(29) TFR(16) TFR(24)
  x0 += ks1; x1 += ks2 + 4u;
  TFR(13) TFR(15) TFR(26) TFR(6)
  x0 += ks2; x1 += ks0 + 5u;
#undef TFR
  o0 = x0; o1 = x1;
}

// Partitionable noise (VERIFIED R7): XOR fold o0^o1 of threefry(key,(0,i))
__device__ __forceinline__ float noise_at(u32 i) {
  u32 o0, o1; tf_0_42(0u, i, o0, o1);
  u32 bits = o0 ^ o1;
  float f = __uint_as_float((bits >> 9) | 0x3F800000u);  // [1,2)
  return 2.0f - f;                                        // 1 - uniform
}

// order-preserving map fp32 -> u32, branchless (finite inputs)
__device__ __forceinline__ u32 map_f32(float v) {
  u32 u = __float_as_uint(v);
  u32 s = (u32)((int)u >> 31);               // 0 or 0xFFFFFFFF
  return u ^ (s | 0x80000000u);
}

// merge two sorted-desc key triples: (a0>=a1>=a2) <- top3 of {a*, b*}
__device__ __forceinline__ void merge3(u64 &a0, u64 &a1, u64 &a2,
                                       u64 b0, u64 b1, u64 b2) {
  u64 o0, o1, o2;
  if (a0 >= b0) {
    o0 = a0;
    if (a1 >= b0) { o1 = a1; o2 = (a2 >= b0) ? a2 : b0; }
    else          { o1 = b0; o2 = (a1 >= b1) ? a1 : b1; }
  } else {
    o0 = b0;
    if (b1 >= a0) { o1 = b1; o2 = (b2 >= a0) ? b2 : a0; }
    else          { o1 = a0; o2 = (b1 >= a1) ? b1 : a1; }
  }
  a0 = o0; a1 = o1; a2 = o2;
}

#define BASE_KEY 0x80000000FFFFFFFFull   // (+0.0, e=0): empty slot -> argmax 0
#define SCALE_   2048.0f
#define INV_SC   (1.0f / 4194304.0f)     // 2^-22

// ---------------- Kernel 1: init keys + prune thresholds ----------------
__global__ __launch_bounds__(256) void init_keys(u64* __restrict__ keys,
                                                 u32* __restrict__ thr) {
  int i = blockIdx.x * 256 + threadIdx.x;    // 32768
  keys[i] = BASE_KEY;
  thr[i]  = 0u;
}

// ---------------- Kernel 1b: pre-split fp32 -> (hi,lo) fp16, scaled by 2^11 ----------------
__device__ __forceinline__ void split8v(const float4 a0, const float4 a1, f16x8 &hi, f16x8 &lo) {
  float fv[8] = {a0.x, a0.y, a0.z, a0.w, a1.x, a1.y, a1.z, a1.w};
#pragma unroll
  for (int j = 0; j < 8; ++j) {
    float f = fv[j] * SCALE_;
    _Float16 h = (_Float16)f;
    hi[j] = h;
    lo[j] = (_Float16)(f - (float)h);
  }
}

__global__ __launch_bounds__(256) void presplit(const float* __restrict__ x,
                                                const float* __restrict__ W,
                                                f16x8* __restrict__ xh, f16x8* __restrict__ xl,
                                                f16x8* __restrict__ wh, f16x8* __restrict__ wl) {
  size_t g = (size_t)blockIdx.x * 256 + threadIdx.x;   // unit = 8 floats
  const float4* src;
  f16x8 *dh, *dl;
  size_t off;
  if (g < XN8_) { src = (const float4*)x; dh = xh; dl = xl; off = g; }
  else          { src = (const float4*)W; dh = wh; dl = wl; off = g - XN8_; }
  float4 a0 = src[off * 2], a1 = src[off * 2 + 1];
  f16x8 hi, lo;
  split8v(a0, a1, hi, lo);
  dh[off] = hi; dl[off] = lo;
}

// ---------------- Kernel 1c: presample pre-warm (t = 32*k sampled rows) ----------------
// Mini-GEMM over 128 sampled t per (b, column); seeds thr with the sampled
// noisy-top-3 3rd-max (subset 3rd-max <= column 3rd-max -> provably safe).
#define BM 128
#define BN 128

__global__ __launch_bounds__(256) void gemm_presample(const f16x8* __restrict__ xh,
                                                      const f16x8* __restrict__ xl,
                                                      const f16x8* __restrict__ wh,
                                                      const f16x8* __restrict__ wl,
                                                      u32* __restrict__ thrbuf) {
  __shared__ f16x8 lds_raw[2048];            // 32 KB
  f16x8* AhV = lds_raw;
  f16x8* AlV = lds_raw + 512;
  f16x8* BhV = lds_raw + 1024;
  f16x8* BlV = lds_raw + 1536;

  const int id = blockIdx.x;                 // 256 blocks
  const int e0 = (id & 31) * BN;
  const int n  = (id >> 5) & 3;
  const int b  = id >> 7;

  const int tid  = threadIdx.x;
  const int lane = tid & 63;
  const int wid  = tid >> 6;
  const int wr   = wid >> 1;
  const int wc   = wid & 1;
  const int lm   = lane & 15;
  const int lk   = lane >> 4;

  f32x4 acc[4][4];
#pragma unroll
  for (int i = 0; i < 4; ++i)
#pragma unroll
    for (int j = 0; j < 4; ++j) acc[i][j] = (f32x4){0.f, 0.f, 0.f, 0.f};

  for (int k0 = 0; k0 < D_ / 8; k0 += 4) {
#pragma unroll
    for (int l = 0; l < 2; ++l) {
      int aid = tid + l * 256;
      int r   = aid >> 2;                    // 0..127 -> t = 32*r
      int ko  = aid & 3;
      int ps  = ko ^ ((r >> 1) & 3);
      size_t gA = ((size_t)(b * T_ + 32 * r) * NB_ + n) * (D_ / 8) + k0 + ko;
      AhV[r * 4 + ps] = xh[gA];
      AlV[r * 4 + ps] = xl[gA];
      size_t gB = ((size_t)n * E_ + e0 + r) * (D_ / 8) + k0 + ko;
      BhV[r * 4 + ps] = wh[gB];
      BlV[r * 4 + ps] = wl[gB];
    }
    __syncthreads();

    f16x8 bh[4], bl[4];
#pragma unroll
    for (int fn = 0; fn < 4; ++fn) {
      int row = wc * 64 + fn * 16 + lm;
      int ps  = lk ^ ((row >> 1) & 3);
      bh[fn] = BhV[row * 4 + ps];
      bl[fn] = BlV[row * 4 + ps];
    }
#pragma unroll
    for (int fm = 0; fm < 4; ++fm) {
      int row = wr * 64 + fm * 16 + lm;
      int ps  = lk ^ ((row >> 1) & 3);
      f16x8 ah = AhV[row * 4 + ps];
      f16x8 al = AlV[row * 4 + ps];
#pragma unroll
      for (int fn = 0; fn < 4; ++fn) {
        acc[fm][fn] = __builtin_amdgcn_mfma_f32_16x16x32_f16(ah, bh[fn], acc[fm][fn], 0, 0, 0);
        acc[fm][fn] = __builtin_amdgcn_mfma_f32_16x16x32_f16(ah, bl[fn], acc[fm][fn], 0, 0, 0);
        acc[fm][fn] = __builtin_amdgcn_mfma_f32_16x16x32_f16(al, bh[fn], acc[fm][fn], 0, 0, 0);
      }
    }
    __syncthreads();
  }
  u64* ldsK = (u64*)lds_raw;                 // repurposed: [4][64][3] u64

#pragma unroll
  for (int fn = 0; fn < 4; ++fn) {
    const int e  = e0 + wc * 64 + fn * 16 + lm;
    const int ne = n * E_ + e;
    u32 v0 = 0, v1 = 0, v2 = 0;
    u32 tt0 = 0, tt1 = 0, tt2 = 0;
    const u32 ibase = (u32)b * HALF_ + (u32)ne;
#pragma unroll
    for (int fm = 0; fm < 4; ++fm) {
#pragma unroll
      for (int r = 0; r < 4; ++r) {
        const u32 t = 32u * (u32)(wr * 64 + fm * 16 + lk * 4 + r);
        float lg = acc[fm][fn][r] * INV_SC;
        u32 mu = __float_as_uint(fmaxf(lg, 0.0f)) | 0x80000000u;
        if (mu > v2) {                        // same rejection as strict-> insert
          float y = lg * noise_at(ibase + t * (u32)NE_);
          u32 mv = map_f32(y);
          bool g0 = mv > v0, g1 = mv > v1, g2 = mv > v2;
          v2  = g1 ? v1  : (g2 ? mv : v2);
          tt2 = g1 ? tt1 : (g2 ? t  : tt2);
          v1  = g0 ? v0  : (g1 ? mv : v1);
          tt1 = g0 ? tt0 : (g1 ? t  : tt1);
          v0  = g0 ? mv  : v0;
          tt0 = g0 ? t   : tt0;
        }
      }
    }
    u64 K0 = ((u64)v0 << 32) | (u64)(0xFFFFFFFFu - tt0);
    u64 K1 = ((u64)v1 << 32) | (u64)(0xFFFFFFFFu - tt1);
    u64 K2 = ((u64)v2 << 32) | (u64)(0xFFFFFFFFu - tt2);
    u64 p0 = __shfl_xor(K0, 16), p1 = __shfl_xor(K1, 16), p2 = __shfl_xor(K2, 16);
    merge3(K0, K1, K2, p0, p1, p2);
    p0 = __shfl_xor(K0, 32); p1 = __shfl_xor(K1, 32); p2 = __shfl_xor(K2, 32);
    merge3(K0, K1, K2, p0, p1, p2);
    if (lk == 0) {
      int c = fn * 16 + lm;
      ldsK[(wid * 64 + c) * 3 + 0] = K0;
      ldsK[(wid * 64 + c) * 3 + 1] = K1;
      ldsK[(wid * 64 + c) * 3 + 2] = K2;
    }
  }
  __syncthreads();
  if (wid < 2) {
    int c = lane;
    u64 A0 = ldsK[(wid * 64 + c) * 3 + 0];
    u64 A1 = ldsK[(wid * 64 + c) * 3 + 1];
    u64 A2 = ldsK[(wid * 64 + c) * 3 + 2];
    merge3(A0, A1, A2,
           ldsK[((wid + 2) * 64 + c) * 3 + 0],
           ldsK[((wid + 2) * 64 + c) * 3 + 1],
           ldsK[((wid + 2) * 64 + c) * 3 + 2]);
    int eg = e0 + wid * 64 + c;
    thrbuf[(size_t)b * NE_ + (size_t)n * E_ + eg] = (u32)(A2 >> 32);  // single writer
  }
}

// ---------------- Kernel 2: fused GEMM + compacted pruned noisy top-3 select ----------------
__global__ __launch_bounds__(256) void gemm_fused(const f16x8* __restrict__ xh,
                                                  const f16x8* __restrict__ xl,
                                                  const f16x8* __restrict__ wh,
                                                  const f16x8* __restrict__ wl,
                                                  float* __restrict__ logits,
                                                  u64* __restrict__ k0g,
                                                  u64* __restrict__ k1g,
                                                  u64* __restrict__ k2g,
                                                  u32* __restrict__ thrbuf) {
  __shared__ f16x8 lds_raw[2048];            // 32 KB, repurposed across phases
  f16x8* AhV = lds_raw;
  f16x8* AlV = lds_raw + 512;
  f16x8* BhV = lds_raw + 1024;
  f16x8* BlV = lds_raw + 1536;

  // B-friendly decode (thr pre-warmed, so warm-up no longer depends on order):
  // e0 fast / mt mid / n slow.  No XCD swizzle (R16 regression reverted).
  const int id = blockIdx.x;
  const int e0 = (id & 31) * BN;
  const int mt = (id >> 5) & 63;
  const int n  = id >> 11;
  const int m0 = mt * BM;                    // m = b*T + t

  const int tid  = threadIdx.x;
  const int lane = tid & 63;
  const int wid  = tid >> 6;                 // 4 waves: wid = wr*2 + wc
  const int wr   = wid >> 1;
  const int wc   = wid & 1;
  const int lm   = lane & 15;
  const int lk   = lane >> 4;                // k-group 0..3

  f32x4 acc[4][4];
#pragma unroll
  for (int i = 0; i < 4; ++i)
#pragma unroll
    for (int j = 0; j < 4; ++j) acc[i][j] = (f32x4){0.f, 0.f, 0.f, 0.f};

  for (int k0 = 0; k0 < D_ / 8; k0 += 4) {   // K-step = 32 halfs = 4 groups
#pragma unroll
    for (int l = 0; l < 2; ++l) {
      int aid = tid + l * 256;               // 0..511
      int r   = aid >> 2;                    // 0..127 (tile row)
      int ko  = aid & 3;                     // k-group
      int ps  = ko ^ ((r >> 1) & 3);         // swizzled slot
      size_t gA = ((size_t)(m0 + r) * NB_ + n) * (D_ / 8) + k0 + ko;
      AhV[r * 4 + ps] = xh[gA];
      AlV[r * 4 + ps] = xl[gA];
      size_t gB = ((size_t)n * E_ + e0 + r) * (D_ / 8) + k0 + ko;
      BhV[r * 4 + ps] = wh[gB];
      BlV[r * 4 + ps] = wl[gB];
    }
    __syncthreads();

    f16x8 bh[4], bl[4];
#pragma unroll
    for (int fn = 0; fn < 4; ++fn) {
      int row = wc * 64 + fn * 16 + lm;
      int ps  = lk ^ ((row >> 1) & 3);
      bh[fn] = BhV[row * 4 + ps];
      bl[fn] = BlV[row * 4 + ps];
    }
#pragma unroll
    for (int fm = 0; fm < 4; ++fm) {
      int row = wr * 64 + fm * 16 + lm;
      int ps  = lk ^ ((row >> 1) & 3);
      f16x8 ah = AhV[row * 4 + ps];
      f16x8 al = AlV[row * 4 + ps];
#pragma unroll
      for (int fn = 0; fn < 4; ++fn) {
        acc[fm][fn] = __builtin_amdgcn_mfma_f32_16x16x32_f16(ah, bh[fn], acc[fm][fn], 0, 0, 0);
        acc[fm][fn] = __builtin_amdgcn_mfma_f32_16x16x32_f16(ah, bl[fn], acc[fm][fn], 0, 0, 0);
        acc[fm][fn] = __builtin_amdgcn_mfma_f32_16x16x32_f16(al, bh[fn], acc[fm][fn], 0, 0, 0);
      }
    }
    __syncthreads();
  }
  // After the final barrier all K-loop LDS reads are done -> repurpose LDS:
  float* lgbuf = (float*)lds_raw;                    // 16 KB: [16 slots][256 threads]
  u16*   tbuf  = (u16*)((char*)lds_raw + 16384);     //  8 KB: [16 slots][256 threads]
  u64*   ldsK  = (u64*)((char*)lds_raw + 24576);     //  6 KB: [4 waves][64 cols][3]

  // ---- epilogue part 1: store logits ----
  const int b     = m0 >> 12;                // m0 / T_
  const int mbase = m0 & (T_ - 1);           // t of tile row 0
  const int mtile = mbase >> 7;

#pragma unroll
  for (int fm = 0; fm < 4; ++fm) {
#pragma unroll
    for (int r = 0; r < 4; ++r) {
      int m = m0 + wr * 64 + fm * 16 + lk * 4 + r;
      float* row = logits + ((size_t)m * NB_ + n) * E_ + e0 + wc * 64 + lm;
#pragma unroll
      for (int fn = 0; fn < 4; ++fn) row[fn * 16] = acc[fm][fn][r] * INV_SC;
    }
  }

  // ---- epilogue part 2: compacted pruned per-column noisy top-3 ----
#pragma unroll
  for (int fn = 0; fn < 4; ++fn) {
    const int e  = e0 + wc * 64 + fn * 16 + lm;   // e within [0,E)
    const int ne = n * E_ + e;
    const u32 thrv = thrbuf[(size_t)b * NE_ + ne];

    // pass 1: compact candidates (lg, t) into LDS
    int cnt = 0;
#pragma unroll
    for (int fm = 0; fm < 4; ++fm) {              // t ascends per lane
#pragma unroll
      for (int r = 0; r < 4; ++r) {
        float lg = acc[fm][fn][r] * INV_SC;
        u32 mu = __float_as_uint(fmaxf(lg, 0.0f)) | 0x80000000u;   // map(ub)
        if (mu >= thrv) {
          lgbuf[cnt * 256 + tid] = lg;
          tbuf [cnt * 256 + tid] = (u16)(mbase + wr * 64 + fm * 16 + lk * 4 + r);
          ++cnt;
        }
      }
    }

    // pass 2: evaluate candidates (wave runs max(cnt) iterations)
    u32 v0 = 0, v1 = 0, v2 = 0;
    u32 tt0 = 0, tt1 = 0, tt2 = 0;
    const u32 ibase = (u32)b * HALF_ + (u32)ne;
    for (int k = 0; k < cnt; ++k) {
      float lg = lgbuf[k * 256 + tid];
      u32 t    = (u32)tbuf[k * 256 + tid];
      float y  = lg * noise_at(ibase + t * (u32)NE_);
      u32 mv = map_f32(y);
      bool g0 = mv > v0, g1 = mv > v1, g2 = mv > v2;
      v2  = g1 ? v1  : (g2 ? mv : v2);
      tt2 = g1 ? tt1 : (g2 ? t  : tt2);
      v1  = g0 ? v0  : (g1 ? mv : v1);
      tt1 = g0 ? tt0 : (g1 ? t  : tt1);
      v0  = g0 ? mv  : v0;
      tt0 = g0 ? t   : tt0;
    }

    u64 K0 = ((u64)v0 << 32) | (u64)(0xFFFFFFFFu - tt0);
    u64 K1 = ((u64)v1 << 32) | (u64)(0xFFFFFFFFu - tt1);
    u64 K2 = ((u64)v2 << 32) | (u64)(0xFFFFFFFFu - tt2);
    // merge across the 4 lk-lanes of this lm-group
    u64 p0 = __shfl_xor(K0, 16), p1 = __shfl_xor(K1, 16), p2 = __shfl_xor(K2, 16);
    merge3(K0, K1, K2, p0, p1, p2);
    p0 = __shfl_xor(K0, 32); p1 = __shfl_xor(K1, 32); p2 = __shfl_xor(K2, 32);
    merge3(K0, K1, K2, p0, p1, p2);
    if (lk == 0) {
      int c = fn * 16 + lm;                  // 0..63
      ldsK[(wid * 64 + c) * 3 + 0] = K0;
      ldsK[(wid * 64 + c) * 3 + 1] = K1;
      ldsK[(wid * 64 + c) * 3 + 2] = K2;
    }
  }
  __syncthreads();
  if (wid < 2) {                             // wr==0 waves merge with their wr==1 partner
    int c = lane;                            // 0..63; e = e0 + wid*64 + c  (wid == wc here)
    u64 A0 = ldsK[(wid * 64 + c) * 3 + 0];
    u64 A1 = ldsK[(wid * 64 + c) * 3 + 1];
    u64 A2 = ldsK[(wid * 64 + c) * 3 + 2];
    u64 C0 = ldsK[((wid + 2) * 64 + c) * 3 + 0];
    u64 C1 = ldsK[((wid + 2) * 64 + c) * 3 + 1];
    u64 C2 = ldsK[((wid + 2) * 64 + c) * 3 + 2];
    merge3(A0, A1, A2, C0, C1, C2);
    int eg = e0 + wid * 64 + c;
    size_t R = (size_t)(mtile * 2 + b) * NE_ + (size_t)n * E_ + eg;
    k0g[R] = A0; k1g[R] = A1; k2g[R] = A2;
    // publish this tile's evaluated-subset 3rd-max as a prune threshold
    atomicMax(&thrbuf[(size_t)b * NE_ + (size_t)n * E_ + eg], (u32)(A2 >> 32));
  }
}

// ---------------- Kernel 3: merge tile records -> global top-3 -> slot scatter ----------------
__global__ __launch_bounds__(256) void merge_scatter2(const u64* __restrict__ k0g,
                                                      const u64* __restrict__ k1g,
                                                      const u64* __restrict__ k2g,
                                                      u64* __restrict__ keys) {
  int gid2 = blockIdx.x * 256 + threadIdx.x;  // 32768 = B*NB*E
  int b  = gid2 >> 14;
  int ne = gid2 & (NE_ - 1);

  u64 K0 = 0, K1 = 0, K2 = 0;
  for (int mt = 0; mt < MT_; ++mt) {
    size_t R = (size_t)(mt * 2 + b) * NE_ + ne;
    merge3(K0, K1, K2, k0g[R], k1g[R], k2g[R]);
  }

  int n = ne >> 12;
  u32 e = (u32)(ne & (E_ - 1));
  u64 elo = (u64)(0xFFFFFFFFu - e);
  u32 t0 = 0xFFFFFFFFu - (u32)K0;
  u32 t1 = 0xFFFFFFFFu - (u32)K1;
  u32 t2 = 0xFFFFFFFFu - (u32)K2;
  atomicMax(&keys[((size_t)b * T_ + t0) * NB_ + n], (K0 & 0xFFFFFFFF00000000ull) | elo);
  atomicMax(&keys[((size_t)b * T_ + t1) * NB_ + n], (K1 & 0xFFFFFFFF00000000ull) | elo);
  atomicMax(&keys[((size_t)b * T_ + t2) * NB_ + n], (K2 & 0xFFFFFFFF00000000ull) | elo);
}

// ---------------- Fallback path (small ws): in-kernel-split GEMM + monolithic select ----------------
__device__ __forceinline__ void split8(const float* __restrict__ p, f16x8 &hi, f16x8 &lo) {
  float4 a0 = *(const float4*)p;
  float4 a1 = *(const float4*)(p + 4);
  split8v(a0, a1, hi, lo);
}

__global__ __launch_bounds__(256) void gemm_logits_fb(const float* __restrict__ x,
                                                      const float* __restrict__ W,
                                                      float* __restrict__ logits) {
  __shared__ f16x8 AhV[128 * 4];
  __shared__ f16x8 AlV[128 * 4];
  __shared__ f16x8 BhV[128 * 4];
  __shared__ f16x8 BlV[128 * 4];

  const int n  = blockIdx.z;
  const int m0 = blockIdx.y * BM;
  const int e0 = blockIdx.x * BN;
  const int tid  = threadIdx.x;
  const int lane = tid & 63;
  const int wid  = tid >> 6;
  const int wr   = wid >> 1;
  const int wc   = wid & 1;
  const int lm   = lane & 15;
  const int lk   = lane >> 4;

  const float* Abase = x + ((size_t)m0 * NB_ + n) * D_;
  const float* Bbase = W + ((size_t)n * E_ + e0) * D_;

  f32x4 acc[4][4];
#pragma unroll
  for (int i = 0; i < 4; ++i)
#pragma unroll
    for (int j = 0; j < 4; ++j) acc[i][j] = (f32x4){0.f, 0.f, 0.f, 0.f};

  for (int k0 = 0; k0 < D_; k0 += 32) {
#pragma unroll
    for (int l = 0; l < 2; ++l) {
      int aid = tid + l * 256;
      int r   = aid >> 2;
      int ko  = aid & 3;
      int ps  = ko ^ ((r >> 1) & 3);
      f16x8 hi, lo;
      split8(Abase + (size_t)r * (NB_ * D_) + k0 + ko * 8, hi, lo);
      AhV[r * 4 + ps] = hi; AlV[r * 4 + ps] = lo;
      split8(Bbase + (size_t)r * D_ + k0 + ko * 8, hi, lo);
      BhV[r * 4 + ps] = hi; BlV[r * 4 + ps] = lo;
    }
    __syncthreads();

    f16x8 bh[4], bl[4];
#pragma unroll
    for (int fn = 0; fn < 4; ++fn) {
      int row = wc * 64 + fn * 16 + lm;
      int ps  = lk ^ ((row >> 1) & 3);
      bh[fn] = BhV[row * 4 + ps];
      bl[fn] = BlV[row * 4 + ps];
    }
#pragma unroll
    for (int fm = 0; fm < 4; ++fm) {
      int row = wr * 64 + fm * 16 + lm;
      int ps  = lk ^ ((row >> 1) & 3);
      f16x8 ah = AhV[row * 4 + ps];
      f16x8 al = AlV[row * 4 + ps];
#pragma unroll
      for (int fn = 0; fn < 4; ++fn) {
        acc[fm][fn] = __builtin_amdgcn_mfma_f32_16x16x32_f16(ah, bh[fn], acc[fm][fn], 0, 0, 0);
        acc[fm][fn] = __builtin_amdgcn_mfma_f32_16x16x32_f16(ah, bl[fn], acc[fm][fn], 0, 0, 0);
        acc[fm][fn] = __builtin_amdgcn_mfma_f32_16x16x32_f16(al, bh[fn], acc[fm][fn], 0, 0, 0);
      }
    }
    __syncthreads();
  }

#pragma unroll
  for (int fm = 0; fm < 4; ++fm) {
#pragma unroll
    for (int fn = 0; fn < 4; ++fn) {
#pragma unroll
      for (int r = 0; r < 4; ++r) {
        int m = m0 + wr * 64 + fm * 16 + lk * 4 + r;
        int e = e0 + wc * 64 + fn * 16 + lm;
        logits[((size_t)m * NB_ + n) * E_ + e] = acc[fm][fn][r] * INV_SC;
      }
    }
  }
}

__global__ __launch_bounds__(256) void select_scatter(const float* __restrict__ logits,
                                                      u64* __restrict__ keys) {
  int gid = blockIdx.x * 256 + threadIdx.x;  // 32768 = B*NB*E
  int b  = gid >> 14;
  int ne = gid & (NE_ - 1);

  float v0 = -1e30f, v1 = -1e30f, v2 = -1e30f;
  int   t0 = 0, t1 = 0, t2 = 0;

  const float* lg = logits + (size_t)b * HALF_;
  const u32 ib = (u32)b * HALF_ + (u32)ne;
  for (int t = 0; t < T_; ++t) {
    u32 i0 = (u32)t * (u32)NE_ + (u32)ne;
    float y = lg[i0] * noise_at(ib + (u32)t * (u32)NE_);
    if (y > v0)      { v2=v1; t2=t1; v1=v0; t1=t0; v0=y; t0=t; }
    else if (y > v1) { v2=v1; t2=t1; v1=y;  t1=t; }
    else if (y > v2) { v2=y;  t2=t; }
  }

  int n = ne >> 12;
  int e = ne & (E_ - 1);
  u64 klo = 0xFFFFFFFFull - (u32)e;
  atomicMax(&keys[((size_t)b * T_ + t0) * NB_ + n], ((u64)map_f32(v0) << 32) | klo);
  atomicMax(&keys[((size_t)b * T_ + t1) * NB_ + n], ((u64)map_f32(v1) << 32) | klo);
  atomicMax(&keys[((size_t)b * T_ + t2) * NB_ + n], ((u64)map_f32(v2) << 32) | klo);
}

// ---------------- Kernel 4: decode argmax -> idx + latent gather ----------------
__global__ __launch_bounds__(128) void finalize(const u64* __restrict__ keys,
                                                const float* __restrict__ W,
                                                float* __restrict__ out_idx,
                                                float* __restrict__ out_lat) {
  int slot = blockIdx.x;                     // (b*T+t)*NB + n
  int n = slot & (NB_ - 1);
  int e = (int)(0xFFFFFFFFu - (u32)keys[slot]) & (E_ - 1);
  if (threadIdx.x == 0) out_idx[slot] = (float)e;

  const float4 v = ((const float4*)(W + ((size_t)n * E_ + e) * D_))[threadIdx.x];
  ((float4*)(out_lat + (size_t)slot * D_))[threadIdx.x] = v;   // 128 x 16B = 2KB
}

// ---------------- Launch ----------------
extern "C" void kernel_launch(void* const* d_in, const int* in_sizes, int n_in,
                              void* d_out, int out_size, void* d_ws, size_t ws_size,
                              hipStream_t stream) {
  const float* x = (const float*)d_in[0];    // [B,T,NB*D] fp32
  const float* W = (const float*)d_in[1];    // [NB,E,D]  fp32

  float* out_idx    = (float*)d_out;                          // 32,768
  float* out_lat    = out_idx + (size_t)SLOTS_;               // 16,777,216
  float* out_logits = out_lat + (size_t)SLOTS_ * D_;          // 134,217,728

  // ws layout: keys | thr | xh | xl | wh | wl
  u64* keys = (u64*)d_ws;
  const size_t KEYS_B = (size_t)SLOTS_ * 8;                   // 256 KiB
  const size_t THR_B  = (size_t)SLOTS_ * 4;                   // 128 KiB
  const size_t XH_B   = (size_t)XN8_ * 16;                    // 32 MiB
  const size_t WH_B   = (size_t)WN8_ * 16;                    // 16 MiB
  bool split = ws_size >= KEYS_B + THR_B + 2 * XH_B + 2 * WH_B;

  u32*   thr = (u32*)((char*)d_ws + KEYS_B);
  char*  sp  = (char*)d_ws + KEYS_B + THR_B;
  f16x8* xh  = (f16x8*)sp;
  f16x8* xl  = (f16x8*)(sp + XH_B);
  f16x8* wh  = (f16x8*)(sp + 2 * XH_B);
  f16x8* wl  = (f16x8*)(sp + 2 * XH_B + WH_B);

  // tile-select records live in the out_lat region (overwritten by finalize later)
  u64* k0g = (u64*)out_lat;                                   // 8 MB each
  u64* k1g = k0g + RECN_;
  u64* k2g = k1g + RECN_;

  init_keys<<<SLOTS_ / 256, 256, 0, stream>>>(keys, thr);

  if (split) {
    presplit<<<(XN8_ + WN8_) / 256, 256, 0, stream>>>(x, W, xh, xl, wh, wl);
    gemm_presample<<<256, 256, 0, stream>>>(xh, xl, wh, wl, thr);
    gemm_fused<<<8192, 256, 0, stream>>>(xh, xl, wh, wl, out_logits, k0g, k1g, k2g, thr);
    merge_scatter2<<<SLOTS_ / 256, 256, 0, stream>>>(k0g, k1g, k2g, keys);
  } else {
    dim3 ggrid(E_ / BN, (B_ * T_) / BM, NB_);
    gemm_logits_fb<<<ggrid, 256, 0, stream>>>(x, W, out_logits);
    select_scatter<<<SLOTS_ / 256, 256, 0, stream>>>(out_logits, keys);
  }

  finalize<<<SLOTS_, 128, 0, stream>>>(keys, W, out_idx, out_lat);
}

// Round 18
// 680.829 us; speedup vs baseline: 1.0832x; 1.0430x over previous
//
#include <hip/hip_runtime.h>
#include <stdint.h>

// Problem constants
#define B_     2
#define T_     4096
#define NB_    4
#define D_     512
#define E_     4096
#define NE_    16384           // NB*E
#define HALF_  67108864u       // T*NB*E  (per-b flat block of [B,T,NB,E])
#define SLOTS_ 32768           // B*T*NB
#define XN8_   2097152         // B*T*NB*D/8
#define WN8_   1048576         // NB*E*D/8
#define MT_    32              // m-tiles per b = T/128
#define RECN_  (64 * NE_)      // (MT_*B) * NE records per key array

typedef unsigned long long u64;
typedef uint32_t u32;
typedef uint16_t u16;
typedef _Float16 f16x8 __attribute__((ext_vector_type(8)));
typedef float    f32x4 __attribute__((ext_vector_type(4)));

// async global->LDS, 16B per lane; LDS dest wave-uniform base + lane*16
#define GLD(srcp, dstp) __builtin_amdgcn_global_load_lds( \
    (const __attribute__((address_space(1))) void*)(srcp), \
    (__attribute__((address_space(3))) void*)(dstp), 16, 0, 0)

// ---------------- Threefry-2x32-20, key = (0, 42) ----------------
__device__ __forceinline__ u32 rotl32(u32 x, int r) { return __builtin_rotateleft32(x, r); }

__device__ __forceinline__ void tf_0_42(u32 x0, u32 x1, u32 &o0, u32 &o1) {
  const u32 ks0 = 0u, ks1 = 42u, ks2 = 0x1BD11BDAu ^ 0u ^ 42u;
  x0 += ks0; x1 += ks1;
#define TFR(r) { x0 += x1; x1 = rotl32(x1, (r)); x1 ^= x0; }
  TFR(13) TFR(15) TFR(26) TFR(6)
  x0 += ks1; x1 += ks2 + 1u;
  TFR(17) TFR(29) TFR(16) TFR(24)
  x0 += ks2; x1 += ks0 + 2u;
  TFR(13) TFR(15) TFR(26) TFR(6)
  x0 += ks0; x1 += ks1 + 3u;
  TFR(17) TFR(29) TFR(16) TFR(24)
  x0 += ks1; x1 += ks2 + 4u;
  TFR(13) TFR(15) TFR(26) TFR(6)
  x0 += ks2; x1 += ks0 + 5u;
#undef TFR
  o0 = x0; o1 = x1;
}

// Partitionable noise (VERIFIED R7): XOR fold o0^o1 of threefry(key,(0,i))
__device__ __forceinline__ float noise_at(u32 i) {
  u32 o0, o1; tf_0_42(0u, i, o0, o1);
  u32 bits = o0 ^ o1;
  float f = __uint_as_float((bits >> 9) | 0x3F800000u);  // [1,2)
  return 2.0f - f;                                        // 1 - uniform
}

// order-preserving map fp32 -> u32, branchless (finite inputs)
__device__ __forceinline__ u32 map_f32(float v) {
  u32 u = __float_as_uint(v);
  u32 s = (u32)((int)u >> 31);               // 0 or 0xFFFFFFFF
  return u ^ (s | 0x80000000u);
}

// merge two sorted-desc key triples: (a0>=a1>=a2) <- top3 of {a*, b*}
__device__ __forceinline__ void merge3(u64 &a0, u64 &a1, u64 &a2,
                                       u64 b0, u64 b1, u64 b2) {
  u64 o0, o1, o2;
  if (a0 >= b0) {
    o0 = a0;
    if (a1 >= b0) { o1 = a1; o2 = (a2 >= b0) ? a2 : b0; }
    else          { o1 = b0; o2 = (a1 >= b1) ? a1 : b1; }
  } else {
    o0 = b0;
    if (b1 >= a0) { o1 = b1; o2 = (b2 >= a0) ? b2 : a0; }
    else          { o1 = a0; o2 = (b1 >= a1) ? b1 : a1; }
  }
  a0 = o0; a1 = o1; a2 = o2;
}

#define BASE_KEY 0x80000000FFFFFFFFull   // (+0.0, e=0): empty slot -> argmax 0
#define SCALE_   2048.0f
#define INV_SC   (1.0f / 4194304.0f)     // 2^-22

// ---------------- Kernel 1: init keys + prune thresholds ----------------
__global__ __launch_bounds__(256) void init_keys(u64* __restrict__ keys,
                                                 u32* __restrict__ thr) {
  int i = blockIdx.x * 256 + threadIdx.x;    // 32768
  keys[i] = BASE_KEY;
  thr[i]  = 0u;
}

// ---------------- Kernel 1b: pre-split fp32 -> (hi,lo) fp16, scaled by 2^11 ----------------
__device__ __forceinline__ void split8v(const float4 a0, const float4 a1, f16x8 &hi, f16x8 &lo) {
  float fv[8] = {a0.x, a0.y, a0.z, a0.w, a1.x, a1.y, a1.z, a1.w};
#pragma unroll
  for (int j = 0; j < 8; ++j) {
    float f = fv[j] * SCALE_;
    _Float16 h = (_Float16)f;
    hi[j] = h;
    lo[j] = (_Float16)(f - (float)h);
  }
}

__global__ __launch_bounds__(256) void presplit(const float* __restrict__ x,
                                                const float* __restrict__ W,
                                                f16x8* __restrict__ xh, f16x8* __restrict__ xl,
                                                f16x8* __restrict__ wh, f16x8* __restrict__ wl) {
  size_t g = (size_t)blockIdx.x * 256 + threadIdx.x;   // unit = 8 floats
  const float4* src;
  f16x8 *dh, *dl;
  size_t off;
  if (g < XN8_) { src = (const float4*)x; dh = xh; dl = xl; off = g; }
  else          { src = (const float4*)W; dh = wh; dl = wl; off = g - XN8_; }
  float4 a0 = src[off * 2], a1 = src[off * 2 + 1];
  f16x8 hi, lo;
  split8v(a0, a1, hi, lo);
  dh[off] = hi; dl[off] = lo;
}

// ---------------- shared GEMM helpers ----------------
#define BM 128
#define BN 128

// async-stage one 32KB K-tile into buf (2048 f16x8 slots: Ah|Al|Bh|Bl @ 512 each).
// slot s: r = s>>2, ps = s&3, source k-group ko = ps ^ ((r>>1)&3) (pre-swizzled src,
// linear LDS dest -> read-side swizzle unchanged; rule #21).
__device__ __forceinline__ void stage_tile(const f16x8* __restrict__ xh,
                                           const f16x8* __restrict__ xl,
                                           const f16x8* __restrict__ wh,
                                           const f16x8* __restrict__ wl,
                                           f16x8* buf, int m0, int n, int e0,
                                           int k0, int w, int lane) {
#pragma unroll
  for (int i = 0; i < 2; ++i) {
    int sbase = w * 128 + i * 64;            // wave-uniform slot base
    int s  = sbase + lane;                   // 0..511
    int r  = s >> 2;                         // tile row
    int ko = (s & 3) ^ ((r >> 1) & 3);       // source k-group
    size_t gA = ((size_t)(m0 + r) * NB_ + n) * (D_ / 8) + k0 + ko;
    size_t gB = ((size_t)n * E_ + e0 + r) * (D_ / 8) + k0 + ko;
    GLD(xh + gA, buf + sbase);
    GLD(xl + gA, buf + 512 + sbase);
    GLD(wh + gB, buf + 1024 + sbase);
    GLD(wl + gB, buf + 1536 + sbase);
  }
}

__device__ __forceinline__ void compute_step(const f16x8* buf, f32x4 acc[4][4],
                                             int wr, int wc, int lm, int lk) {
  const f16x8* Ah = buf;
  const f16x8* Al = buf + 512;
  const f16x8* Bh = buf + 1024;
  const f16x8* Bl = buf + 1536;
  f16x8 bh[4], bl[4];
#pragma unroll
  for (int fn = 0; fn < 4; ++fn) {
    int row = wc * 64 + fn * 16 + lm;
    int ps  = lk ^ ((row >> 1) & 3);
    bh[fn] = Bh[row * 4 + ps];
    bl[fn] = Bl[row * 4 + ps];
  }
#pragma unroll
  for (int fm = 0; fm < 4; ++fm) {
    int row = wr * 64 + fm * 16 + lm;
    int ps  = lk ^ ((row >> 1) & 3);
    f16x8 ah = Ah[row * 4 + ps];
    f16x8 al = Al[row * 4 + ps];
#pragma unroll
    for (int fn = 0; fn < 4; ++fn) {
      acc[fm][fn] = __builtin_amdgcn_mfma_f32_16x16x32_f16(ah, bh[fn], acc[fm][fn], 0, 0, 0);
      acc[fm][fn] = __builtin_amdgcn_mfma_f32_16x16x32_f16(ah, bl[fn], acc[fm][fn], 0, 0, 0);
      acc[fm][fn] = __builtin_amdgcn_mfma_f32_16x16x32_f16(al, bh[fn], acc[fm][fn], 0, 0, 0);
    }
  }
}

// ---------------- Kernel 1c: presample pre-warm (t = 32*k sampled rows) ----------------
__global__ __launch_bounds__(256) void gemm_presample(const f16x8* __restrict__ xh,
                                                      const f16x8* __restrict__ xl,
                                                      const f16x8* __restrict__ wh,
                                                      const f16x8* __restrict__ wl,
                                                      u32* __restrict__ thrbuf) {
  __shared__ f16x8 lds_raw[2048];            // 32 KB
  f16x8* AhV = lds_raw;
  f16x8* AlV = lds_raw + 512;
  f16x8* BhV = lds_raw + 1024;
  f16x8* BlV = lds_raw + 1536;

  const int id = blockIdx.x;                 // 256 blocks
  const int e0 = (id & 31) * BN;
  const int n  = (id >> 5) & 3;
  const int b  = id >> 7;

  const int tid  = threadIdx.x;
  const int lane = tid & 63;
  const int wid  = tid >> 6;
  const int wr   = wid >> 1;
  const int wc   = wid & 1;
  const int lm   = lane & 15;
  const int lk   = lane >> 4;

  f32x4 acc[4][4];
#pragma unroll
  for (int i = 0; i < 4; ++i)
#pragma unroll
    for (int j = 0; j < 4; ++j) acc[i][j] = (f32x4){0.f, 0.f, 0.f, 0.f};

  for (int k0 = 0; k0 < D_ / 8; k0 += 4) {
#pragma unroll
    for (int l = 0; l < 2; ++l) {
      int aid = tid + l * 256;
      int r   = aid >> 2;                    // 0..127 -> t = 32*r
      int ko  = aid & 3;
      int ps  = ko ^ ((r >> 1) & 3);
      size_t gA = ((size_t)(b * T_ + 32 * r) * NB_ + n) * (D_ / 8) + k0 + ko;
      AhV[r * 4 + ps] = xh[gA];
      AlV[r * 4 + ps] = xl[gA];
      size_t gB = ((size_t)n * E_ + e0 + r) * (D_ / 8) + k0 + ko;
      BhV[r * 4 + ps] = wh[gB];
      BlV[r * 4 + ps] = wl[gB];
    }
    __syncthreads();
    compute_step(lds_raw, acc, wr, wc, lm, lk);
    __syncthreads();
  }
  u64* ldsK = (u64*)lds_raw;                 // repurposed: [4][64][3] u64

#pragma unroll
  for (int fn = 0; fn < 4; ++fn) {
    const int e  = e0 + wc * 64 + fn * 16 + lm;
    const int ne = n * E_ + e;
    u32 v0 = 0, v1 = 0, v2 = 0;
    u32 tt0 = 0, tt1 = 0, tt2 = 0;
    const u32 ibase = (u32)b * HALF_ + (u32)ne;
#pragma unroll
    for (int fm = 0; fm < 4; ++fm) {
#pragma unroll
      for (int r = 0; r < 4; ++r) {
        const u32 t = 32u * (u32)(wr * 64 + fm * 16 + lk * 4 + r);
        float lg = acc[fm][fn][r] * INV_SC;
        u32 mu = __float_as_uint(fmaxf(lg, 0.0f)) | 0x80000000u;
        if (mu > v2) {                        // same rejection as strict-> insert
          float y = lg * noise_at(ibase + t * (u32)NE_);
          u32 mv = map_f32(y);
          bool g0 = mv > v0, g1 = mv > v1, g2 = mv > v2;
          v2  = g1 ? v1  : (g2 ? mv : v2);
          tt2 = g1 ? tt1 : (g2 ? t  : tt2);
          v1  = g0 ? v0  : (g1 ? mv : v1);
          tt1 = g0 ? tt0 : (g1 ? t  : tt1);
          v0  = g0 ? mv  : v0;
          tt0 = g0 ? t   : tt0;
        }
      }
    }
    u64 K0 = ((u64)v0 << 32) | (u64)(0xFFFFFFFFu - tt0);
    u64 K1 = ((u64)v1 << 32) | (u64)(0xFFFFFFFFu - tt1);
    u64 K2 = ((u64)v2 << 32) | (u64)(0xFFFFFFFFu - tt2);
    u64 p0 = __shfl_xor(K0, 16), p1 = __shfl_xor(K1, 16), p2 = __shfl_xor(K2, 16);
    merge3(K0, K1, K2, p0, p1, p2);
    p0 = __shfl_xor(K0, 32); p1 = __shfl_xor(K1, 32); p2 = __shfl_xor(K2, 32);
    merge3(K0, K1, K2, p0, p1, p2);
    if (lk == 0) {
      int c = fn * 16 + lm;
      ldsK[(wid * 64 + c) * 3 + 0] = K0;
      ldsK[(wid * 64 + c) * 3 + 1] = K1;
      ldsK[(wid * 64 + c) * 3 + 2] = K2;
    }
  }
  __syncthreads();
  if (wid < 2) {
    int c = lane;
    u64 A0 = ldsK[(wid * 64 + c) * 3 + 0];
    u64 A1 = ldsK[(wid * 64 + c) * 3 + 1];
    u64 A2 = ldsK[(wid * 64 + c) * 3 + 2];
    merge3(A0, A1, A2,
           ldsK[((wid + 2) * 64 + c) * 3 + 0],
           ldsK[((wid + 2) * 64 + c) * 3 + 1],
           ldsK[((wid + 2) * 64 + c) * 3 + 2]);
    int eg = e0 + wid * 64 + c;
    thrbuf[(size_t)b * NE_ + (size_t)n * E_ + eg] = (u32)(A2 >> 32);  // single writer
  }
}

// ---------------- Kernel 2: fused GEMM (2-phase dbuf + global_load_lds) + select ----------------
__global__ __launch_bounds__(256) void gemm_fused(const f16x8* __restrict__ xh,
                                                  const f16x8* __restrict__ xl,
                                                  const f16x8* __restrict__ wh,
                                                  const f16x8* __restrict__ wl,
                                                  float* __restrict__ logits,
                                                  u64* __restrict__ k0g,
                                                  u64* __restrict__ k1g,
                                                  u64* __restrict__ k2g,
                                                  u32* __restrict__ thrbuf) {
  __shared__ f16x8 lds_raw[4096];            // 64 KB: two 2048-slot K-tile buffers
  f16x8* bufA = lds_raw;
  f16x8* bufB = lds_raw + 2048;

  // decode: e0 fast / mt mid / n slow (R17)
  const int id = blockIdx.x;
  const int e0 = (id & 31) * BN;
  const int mt = (id >> 5) & 63;
  const int n  = id >> 11;
  const int m0 = mt * BM;                    // m = b*T + t

  const int tid  = threadIdx.x;
  const int lane = tid & 63;
  const int wid  = tid >> 6;                 // 4 waves: wid = wr*2 + wc
  const int wr   = wid >> 1;
  const int wc   = wid & 1;
  const int lm   = lane & 15;
  const int lk   = lane >> 4;                // k-group 0..3

  f32x4 acc[4][4];
#pragma unroll
  for (int i = 0; i < 4; ++i)
#pragma unroll
    for (int j = 0; j < 4; ++j) acc[i][j] = (f32x4){0.f, 0.f, 0.f, 0.f};

  // 2-phase pipeline: 16 K-steps (k0 = 4*kk), stage(next) issued BEFORE compute(cur)
  stage_tile(xh, xl, wh, wl, bufA, m0, n, e0, 0, wid, lane);
  __syncthreads();                           // drains vmcnt -> bufA ready
  for (int kk = 0; kk < 16; kk += 2) {
    stage_tile(xh, xl, wh, wl, bufB, m0, n, e0, 4 * (kk + 1), wid, lane);
    compute_step(bufA, acc, wr, wc, lm, lk);
    __syncthreads();                         // bufB ready; bufA reads done
    if (kk < 14)
      stage_tile(xh, xl, wh, wl, bufA, m0, n, e0, 4 * (kk + 2), wid, lane);
    compute_step(bufB, acc, wr, wc, lm, lk);
    __syncthreads();                         // bufA ready; bufB reads done
  }

  // LDS repurpose for epilogue:
  float* lgbuf = (float*)lds_raw;                    // 16 KB: [16 slots][256 threads]
  u16*   tbuf  = (u16*)((char*)lds_raw + 16384);     //  8 KB: [16 slots][256 threads]
  u64*   ldsK  = (u64*)((char*)lds_raw + 24576);     //  6 KB: [4 waves][64 cols][3]

  // ---- epilogue part 1: store logits ----
  const int b     = m0 >> 12;                // m0 / T_
  const int mbase = m0 & (T_ - 1);           // t of tile row 0
  const int mtile = mbase >> 7;

#pragma unroll
  for (int fm = 0; fm < 4; ++fm) {
#pragma unroll
    for (int r = 0; r < 4; ++r) {
      int m = m0 + wr * 64 + fm * 16 + lk * 4 + r;
      float* row = logits + ((size_t)m * NB_ + n) * E_ + e0 + wc * 64 + lm;
#pragma unroll
      for (int fn = 0; fn < 4; ++fn) row[fn * 16] = acc[fm][fn][r] * INV_SC;
    }
  }

  // ---- epilogue part 2: compacted pruned per-column noisy top-3 ----
#pragma unroll
  for (int fn = 0; fn < 4; ++fn) {
    const int e  = e0 + wc * 64 + fn * 16 + lm;   // e within [0,E)
    const int ne = n * E_ + e;
    const u32 thrv = thrbuf[(size_t)b * NE_ + ne];

    // pass 1: compact candidates (lg, t) into LDS
    int cnt = 0;
#pragma unroll
    for (int fm = 0; fm < 4; ++fm) {              // t ascends per lane
#pragma unroll
      for (int r = 0; r < 4; ++r) {
        float lg = acc[fm][fn][r] * INV_SC;
        u32 mu = __float_as_uint(fmaxf(lg, 0.0f)) | 0x80000000u;   // map(ub)
        if (mu >= thrv) {
          lgbuf[cnt * 256 + tid] = lg;
          tbuf [cnt * 256 + tid] = (u16)(mbase + wr * 64 + fm * 16 + lk * 4 + r);
          ++cnt;
        }
      }
    }

    // pass 2: evaluate candidates (wave runs max(cnt) iterations)
    u32 v0 = 0, v1 = 0, v2 = 0;
    u32 tt0 = 0, tt1 = 0, tt2 = 0;
    const u32 ibase = (u32)b * HALF_ + (u32)ne;
    for (int k = 0; k < cnt; ++k) {
      float lg = lgbuf[k * 256 + tid];
      u32 t    = (u32)tbuf[k * 256 + tid];
      float y  = lg * noise_at(ibase + t * (u32)NE_);
      u32 mv = map_f32(y);
      bool g0 = mv > v0, g1 = mv > v1, g2 = mv > v2;
      v2  = g1 ? v1  : (g2 ? mv : v2);
      tt2 = g1 ? tt1 : (g2 ? t  : tt2);
      v1  = g0 ? v0  : (g1 ? mv : v1);
      tt1 = g0 ? tt0 : (g1 ? t  : tt1);
      v0  = g0 ? mv  : v0;
      tt0 = g0 ? t   : tt0;
    }

    u64 K0 = ((u64)v0 << 32) | (u64)(0xFFFFFFFFu - tt0);
    u64 K1 = ((u64)v1 << 32) | (u64)(0xFFFFFFFFu - tt1);
    u64 K2 = ((u64)v2 << 32) | (u64)(0xFFFFFFFFu - tt2);
    // merge across the 4 lk-lanes of this lm-group
    u64 p0 = __shfl_xor(K0, 16), p1 = __shfl_xor(K1, 16), p2 = __shfl_xor(K2, 16);
    merge3(K0, K1, K2, p0, p1, p2);
    p0 = __shfl_xor(K0, 32); p1 = __shfl_xor(K1, 32); p2 = __shfl_xor(K2, 32);
    merge3(K0, K1, K2, p0, p1, p2);
    if (lk == 0) {
      int c = fn * 16 + lm;                  // 0..63
      ldsK[(wid * 64 + c) * 3 + 0] = K0;
      ldsK[(wid * 64 + c) * 3 + 1] = K1;
      ldsK[(wid * 64 + c) * 3 + 2] = K2;
    }
  }
  __syncthreads();
  if (wid < 2) {                             // wr==0 waves merge with their wr==1 partner
    int c = lane;                            // 0..63; e = e0 + wid*64 + c  (wid == wc here)
    u64 A0 = ldsK[(wid * 64 + c) * 3 + 0];
    u64 A1 = ldsK[(wid * 64 + c) * 3 + 1];
    u64 A2 = ldsK[(wid * 64 + c) * 3 + 2];
    u64 C0 = ldsK[((wid + 2) * 64 + c) * 3 + 0];
    u64 C1 = ldsK[((wid + 2) * 64 + c) * 3 + 1];
    u64 C2 = ldsK[((wid + 2) * 64 + c) * 3 + 2];
    merge3(A0, A1, A2, C0, C1, C2);
    int eg = e0 + wid * 64 + c;
    size_t R = (size_t)(mtile * 2 + b) * NE_ + (size_t)n * E_ + eg;
    k0g[R] = A0; k1g[R] = A1; k2g[R] = A2;
    // publish this tile's evaluated-subset 3rd-max as a prune threshold
    atomicMax(&thrbuf[(size_t)b * NE_ + (size_t)n * E_ + eg], (u32)(A2 >> 32));
  }
}

// ---------------- Kernel 3: merge tile records -> global top-3 -> slot scatter ----------------
__global__ __launch_bounds__(256) void merge_scatter2(const u64* __restrict__ k0g,
                                                      const u64* __restrict__ k1g,
                                                      const u64* __restrict__ k2g,
                                                      u64* __restrict__ keys) {
  int gid2 = blockIdx.x * 256 + threadIdx.x;  // 32768 = B*NB*E
  int b  = gid2 >> 14;
  int ne = gid2 & (NE_ - 1);

  u64 K0 = 0, K1 = 0, K2 = 0;
  for (int mt = 0; mt < MT_; ++mt) {
    size_t R = (size_t)(mt * 2 + b) * NE_ + ne;
    merge3(K0, K1, K2, k0g[R], k1g[R], k2g[R]);
  }

  int n = ne >> 12;
  u32 e = (u32)(ne & (E_ - 1));
  u64 elo = (u64)(0xFFFFFFFFu - e);
  u32 t0 = 0xFFFFFFFFu - (u32)K0;
  u32 t1 = 0xFFFFFFFFu - (u32)K1;
  u32 t2 = 0xFFFFFFFFu - (u32)K2;
  atomicMax(&keys[((size_t)b * T_ + t0) * NB_ + n], (K0 & 0xFFFFFFFF00000000ull) | elo);
  atomicMax(&keys[((size_t)b * T_ + t1) * NB_ + n], (K1 & 0xFFFFFFFF00000000ull) | elo);
  atomicMax(&keys[((size_t)b * T_ + t2) * NB_ + n], (K2 & 0xFFFFFFFF00000000ull) | elo);
}

// ---------------- Fallback path (small ws): in-kernel-split GEMM + monolithic select ----------------
__device__ __forceinline__ void split8(const float* __restrict__ p, f16x8 &hi, f16x8 &lo) {
  float4 a0 = *(const float4*)p;
  float4 a1 = *(const float4*)(p + 4);
  split8v(a0, a1, hi, lo);
}

__global__ __launch_bounds__(256) void gemm_logits_fb(const float* __restrict__ x,
                                                      const float* __restrict__ W,
                                                      float* __restrict__ logits) {
  __shared__ f16x8 lds_raw[2048];
  f16x8* AhV = lds_raw;
  f16x8* AlV = lds_raw + 512;
  f16x8* BhV = lds_raw + 1024;
  f16x8* BlV = lds_raw + 1536;

  const int n  = blockIdx.z;
  const int m0 = blockIdx.y * BM;
  const int e0 = blockIdx.x * BN;
  const int tid  = threadIdx.x;
  const int lane = tid & 63;
  const int wid  = tid >> 6;
  const int wr   = wid >> 1;
  const int wc   = wid & 1;
  const int lm   = lane & 15;
  const int lk   = lane >> 4;

  const float* Abase = x + ((size_t)m0 * NB_ + n) * D_;
  const float* Bbase = W + ((size_t)n * E_ + e0) * D_;

  f32x4 acc[4][4];
#pragma unroll
  for (int i = 0; i < 4; ++i)
#pragma unroll
    for (int j = 0; j < 4; ++j) acc[i][j] = (f32x4){0.f, 0.f, 0.f, 0.f};

  for (int k0 = 0; k0 < D_; k0 += 32) {
#pragma unroll
    for (int l = 0; l < 2; ++l) {
      int aid = tid + l * 256;
      int r   = aid >> 2;
      int ko  = aid & 3;
      int ps  = ko ^ ((r >> 1) & 3);
      f16x8 hi, lo;
      split8(Abase + (size_t)r * (NB_ * D_) + k0 + ko * 8, hi, lo);
      AhV[r * 4 + ps] = hi; AlV[r * 4 + ps] = lo;
      split8(Bbase + (size_t)r * D_ + k0 + ko * 8, hi, lo);
      BhV[r * 4 + ps] = hi; BlV[r * 4 + ps] = lo;
    }
    __syncthreads();
    compute_step(lds_raw, acc, wr, wc, lm, lk);
    __syncthreads();
  }

#pragma unroll
  for (int fm = 0; fm < 4; ++fm) {
#pragma unroll
    for (int fn = 0; fn < 4; ++fn) {
#pragma unroll
      for (int r = 0; r < 4; ++r) {
        int m = m0 + wr * 64 + fm * 16 + lk * 4 + r;
        int e = e0 + wc * 64 + fn * 16 + lm;
        logits[((size_t)m * NB_ + n) * E_ + e] = acc[fm][fn][r] * INV_SC;
      }
    }
  }
}

__global__ __launch_bounds__(256) void select_scatter(const float* __restrict__ logits,
                                                      u64* __restrict__ keys) {
  int gid = blockIdx.x * 256 + threadIdx.x;  // 32768 = B*NB*E
  int b  = gid >> 14;
  int ne = gid & (NE_ - 1);

  float v0 = -1e30f, v1 = -1e30f, v2 = -1e30f;
  int   t0 = 0, t1 = 0, t2 = 0;

  const float* lg = logits + (size_t)b * HALF_;
  const u32 ib = (u32)b * HALF_ + (u32)ne;
  for (int t = 0; t < T_; ++t) {
    u32 i0 = (u32)t * (u32)NE_ + (u32)ne;
    float y = lg[i0] * noise_at(ib + (u32)t * (u32)NE_);
    if (y > v0)      { v2=v1; t2=t1; v1=v0; t1=t0; v0=y; t0=t; }
    else if (y > v1) { v2=v1; t2=t1; v1=y;  t1=t; }
    else if (y > v2) { v2=y;  t2=t; }
  }

  int n = ne >> 12;
  int e = ne & (E_ - 1);
  u64 klo = 0xFFFFFFFFull - (u32)e;
  atomicMax(&keys[((size_t)b * T_ + t0) * NB_ + n], ((u64)map_f32(v0) << 32) | klo);
  atomicMax(&keys[((size_t)b * T_ + t1) * NB_ + n], ((u64)map_f32(v1) << 32) | klo);
  atomicMax(&keys[((size_t)b * T_ + t2) * NB_ + n], ((u64)map_f32(v2) << 32) | klo);
}

// ---------------- Kernel 4: decode argmax -> idx + latent gather ----------------
__global__ __launch_bounds__(128) void finalize(const u64* __restrict__ keys,
                                                const float* __restrict__ W,
                                                float* __restrict__ out_idx,
                                                float* __restrict__ out_lat) {
  int slot = blockIdx.x;                     // (b*T+t)*NB + n
  int n = slot & (NB_ - 1);
  int e = (int)(0xFFFFFFFFu - (u32)keys[slot]) & (E_ - 1);
  if (threadIdx.x == 0) out_idx[slot] = (float)e;

  const float4 v = ((const float4*)(W + ((size_t)n * E_ + e) * D_))[threadIdx.x];
  ((float4*)(out_lat + (size_t)slot * D_))[threadIdx.x] = v;   // 128 x 16B = 2KB
}

// ---------------- Launch ----------------
extern "C" void kernel_launch(void* const* d_in, const int* in_sizes, int n_in,
                              void* d_out, int out_size, void* d_ws, size_t ws_size,
                              hipStream_t stream) {
  const float* x = (const float*)d_in[0];    // [B,T,NB*D] fp32
  const float* W = (const float*)d_in[1];    // [NB,E,D]  fp32

  float* out_idx    = (float*)d_out;                          // 32,768
  float* out_lat    = out_idx + (size_t)SLOTS_;               // 16,777,216
  float* out_logits = out_lat + (size_t)SLOTS_ * D_;          // 134,217,728

  // ws layout: keys | thr | xh | xl | wh | wl
  u64* keys = (u64*)d_ws;
  const size_t KEYS_B = (size_t)SLOTS_ * 8;                   // 256 KiB
  const size_t THR_B  = (size_t)SLOTS_ * 4;                   // 128 KiB
  const size_t XH_B   = (size_t)XN8_ * 16;                    // 32 MiB
  const size_t WH_B   = (size_t)WN8_ * 16;                    // 16 MiB
  bool split = ws_size >= KEYS_B + THR_B + 2 * XH_B + 2 * WH_B;

  u32*   thr = (u32*)((char*)d_ws + KEYS_B);
  char*  sp  = (char*)d_ws + KEYS_B + THR_B;
  f16x8* xh  = (f16x8*)sp;
  f16x8* xl  = (f16x8*)(sp + XH_B);
  f16x8* wh  = (f16x8*)(sp + 2 * XH_B);
  f16x8* wl  = (f16x8*)(sp + 2 * XH_B + WH_B);

  // tile-select records live in the out_lat region (overwritten by finalize later)
  u64* k0g = (u64*)out_lat;                                   // 8 MB each
  u64* k1g = k0g + RECN_;
  u64* k2g = k1g + RECN_;

  init_keys<<<SLOTS_ / 256, 256, 0, stream>>>(keys, thr);

  if (split) {
    presplit<<<(XN8_ + WN8_) / 256, 256, 0, stream>>>(x, W, xh, xl, wh, wl);
    gemm_presample<<<256, 256, 0, stream>>>(xh, xl, wh, wl, thr);
    gemm_fused<<<8192, 256, 0, stream>>>(xh, xl, wh, wl, out_logits, k0g, k1g, k2g, thr);
    merge_scatter2<<<SLOTS_ / 256, 256, 0, stream>>>(k0g, k1g, k2g, keys);
  } else {
    dim3 ggrid(E_ / BN, (B_ * T_) / BM, NB_);
    gemm_logits_fb<<<ggrid, 256, 0, stream>>>(x, W, out_logits);
    select_scatter<<<SLOTS_ / 256, 256, 0, stream>>>(out_logits, keys);
  }

  finalize<<<SLOTS_, 128, 0, stream>>>(keys, W, out_idx, out_lat);
}

// Round 19
// 611.530 us; speedup vs baseline: 1.2059x; 1.1133x over previous
//
#include <hip/hip_runtime.h>
#include <stdint.h>

// Problem constants
#define B_     2
#define T_     4096
#define NB_    4
#define D_     512
#define E_     4096
#define NE_    16384           // NB*E
#define HALF_  67108864u       // T*NB*E  (per-b flat block of [B,T,NB,E])
#define SLOTS_ 32768           // B*T*NB
#define XN8_   2097152         // B*T*NB*D/8
#define WN8_   1048576         // NB*E*D/8
#define MT_    32              // m-tiles per b = T/128
#define RECN_  (64 * NE_)      // (MT_*B) * NE records per key array

typedef unsigned long long u64;
typedef uint32_t u32;
typedef uint16_t u16;
typedef _Float16 f16x8 __attribute__((ext_vector_type(8)));
typedef float    f32x4 __attribute__((ext_vector_type(4)));

// async global->LDS, 16B per lane; LDS dest wave-uniform base + lane*16
#define GLD(srcp, dstp) __builtin_amdgcn_global_load_lds( \
    (const __attribute__((address_space(1))) void*)(srcp), \
    (__attribute__((address_space(3))) void*)(dstp), 16, 0, 0)

// ---------------- Threefry-2x32-20, key = (0, 42) ----------------
__device__ __forceinline__ u32 rotl32(u32 x, int r) { return __builtin_rotateleft32(x, r); }

__device__ __forceinline__ void tf_0_42(u32 x0, u32 x1, u32 &o0, u32 &o1) {
  const u32 ks0 = 0u, ks1 = 42u, ks2 = 0x1BD11BDAu ^ 0u ^ 42u;
  x0 += ks0; x1 += ks1;
#define TFR(r) { x0 += x1; x1 = rotl32(x1, (r)); x1 ^= x0; }
  TFR(13) TFR(15) TFR(26) TFR(6)
  x0 += ks1; x1 += ks2 + 1u;
  TFR(17) TFR(29) TFR(16) TFR(24)
  x0 += ks2; x1 += ks0 + 2u;
  TFR(13) TFR(15) TFR(26) TFR(6)
  x0 += ks0; x1 += ks1 + 3u;
  TFR(17) TFR(29) TFR(16) TFR(24)
  x0 += ks1; x1 += ks2 + 4u;
  TFR(13) TFR(15) TFR(26) TFR(6)
  x0 += ks2; x1 += ks0 + 5u;
#undef TFR
  o0 = x0; o1 = x1;
}

// Partitionable noise (VERIFIED R7): XOR fold o0^o1 of threefry(key,(0,i))
__device__ __forceinline__ float noise_at(u32 i) {
  u32 o0, o1; tf_0_42(0u, i, o0, o1);
  u32 bits = o0 ^ o1;
  float f = __uint_as_float((bits >> 9) | 0x3F800000u);  // [1,2)
  return 2.0f - f;                                        // 1 - uniform
}

// order-preserving map fp32 -> u32, branchless (finite inputs)
__device__ __forceinline__ u32 map_f32(float v) {
  u32 u = __float_as_uint(v);
  u32 s = (u32)((int)u >> 31);               // 0 or 0xFFFFFFFF
  return u ^ (s | 0x80000000u);
}

// merge two sorted-desc key triples: (a0>=a1>=a2) <- top3 of {a*, b*}
__device__ __forceinline__ void merge3(u64 &a0, u64 &a1, u64 &a2,
                                       u64 b0, u64 b1, u64 b2) {
  u64 o0, o1, o2;
  if (a0 >= b0) {
    o0 = a0;
    if (a1 >= b0) { o1 = a1; o2 = (a2 >= b0) ? a2 : b0; }
    else          { o1 = b0; o2 = (a1 >= b1) ? a1 : b1; }
  } else {
    o0 = b0;
    if (b1 >= a0) { o1 = b1; o2 = (b2 >= a0) ? b2 : a0; }
    else          { o1 = a0; o2 = (b1 >= a1) ? b1 : a1; }
  }
  a0 = o0; a1 = o1; a2 = o2;
}

#define BASE_KEY 0x80000000FFFFFFFFull   // (+0.0, e=0): empty slot -> argmax 0
#define SCALE_   2048.0f
#define INV_SC   (1.0f / 4194304.0f)     // 2^-22

// ---------------- Kernel 1: init keys + prune thresholds ----------------
__global__ __launch_bounds__(256) void init_keys(u64* __restrict__ keys,
                                                 u32* __restrict__ thr) {
  int i = blockIdx.x * 256 + threadIdx.x;    // 32768
  keys[i] = BASE_KEY;
  thr[i]  = 0u;
}

// ---------------- Kernel 1b: pre-split fp32 -> (hi,lo) fp16, scaled by 2^11 ----------------
__device__ __forceinline__ void split8v(const float4 a0, const float4 a1, f16x8 &hi, f16x8 &lo) {
  float fv[8] = {a0.x, a0.y, a0.z, a0.w, a1.x, a1.y, a1.z, a1.w};
#pragma unroll
  for (int j = 0; j < 8; ++j) {
    float f = fv[j] * SCALE_;
    _Float16 h = (_Float16)f;
    hi[j] = h;
    lo[j] = (_Float16)(f - (float)h);
  }
}

__global__ __launch_bounds__(256) void presplit(const float* __restrict__ x,
                                                const float* __restrict__ W,
                                                f16x8* __restrict__ xh, f16x8* __restrict__ xl,
                                                f16x8* __restrict__ wh, f16x8* __restrict__ wl) {
  size_t g = (size_t)blockIdx.x * 256 + threadIdx.x;   // unit = 8 floats
  const float4* src;
  f16x8 *dh, *dl;
  size_t off;
  if (g < XN8_) { src = (const float4*)x; dh = xh; dl = xl; off = g; }
  else          { src = (const float4*)W; dh = wh; dl = wl; off = g - XN8_; }
  float4 a0 = src[off * 2], a1 = src[off * 2 + 1];
  f16x8 hi, lo;
  split8v(a0, a1, hi, lo);
  dh[off] = hi; dl[off] = lo;
}

// ---------------- shared GEMM helpers ----------------
#define BM 128
#define BN 128

// async-stage one 32KB K-tile into buf (2048 f16x8 slots: Ah|Al|Bh|Bl @ 512 each).
// slot s: r = s>>2, ps = s&3, source k-group ko = ps ^ ((r>>1)&3) (pre-swizzled src,
// linear LDS dest -> read-side swizzle unchanged; rule #21).
__device__ __forceinline__ void stage_tile(const f16x8* __restrict__ xh,
                                           const f16x8* __restrict__ xl,
                                           const f16x8* __restrict__ wh,
                                           const f16x8* __restrict__ wl,
                                           f16x8* buf, int m0, int n, int e0,
                                           int k0, int w, int lane) {
#pragma unroll
  for (int i = 0; i < 2; ++i) {
    int sbase = w * 128 + i * 64;            // wave-uniform slot base
    int s  = sbase + lane;                   // 0..511
    int r  = s >> 2;                         // tile row
    int ko = (s & 3) ^ ((r >> 1) & 3);       // source k-group
    size_t gA = ((size_t)(m0 + r) * NB_ + n) * (D_ / 8) + k0 + ko;
    size_t gB = ((size_t)n * E_ + e0 + r) * (D_ / 8) + k0 + ko;
    GLD(xh + gA, buf + sbase);
    GLD(xl + gA, buf + 512 + sbase);
    GLD(wh + gB, buf + 1024 + sbase);
    GLD(wl + gB, buf + 1536 + sbase);
  }
}

__device__ __forceinline__ void compute_step(const f16x8* buf, f32x4 acc[4][4],
                                             int wr, int wc, int lm, int lk) {
  const f16x8* Ah = buf;
  const f16x8* Al = buf + 512;
  const f16x8* Bh = buf + 1024;
  const f16x8* Bl = buf + 1536;
  f16x8 bh[4], bl[4];
#pragma unroll
  for (int fn = 0; fn < 4; ++fn) {
    int row = wc * 64 + fn * 16 + lm;
    int ps  = lk ^ ((row >> 1) & 3);
    bh[fn] = Bh[row * 4 + ps];
    bl[fn] = Bl[row * 4 + ps];
  }
#pragma unroll
  for (int fm = 0; fm < 4; ++fm) {
    int row = wr * 64 + fm * 16 + lm;
    int ps  = lk ^ ((row >> 1) & 3);
    f16x8 ah = Ah[row * 4 + ps];
    f16x8 al = Al[row * 4 + ps];
#pragma unroll
    for (int fn = 0; fn < 4; ++fn) {
      acc[fm][fn] = __builtin_amdgcn_mfma_f32_16x16x32_f16(ah, bh[fn], acc[fm][fn], 0, 0, 0);
      acc[fm][fn] = __builtin_amdgcn_mfma_f32_16x16x32_f16(ah, bl[fn], acc[fm][fn], 0, 0, 0);
      acc[fm][fn] = __builtin_amdgcn_mfma_f32_16x16x32_f16(al, bh[fn], acc[fm][fn], 0, 0, 0);
    }
  }
}

// ---------------- Kernel 1c: presample pre-warm (t = 32*k sampled rows) ----------------
__global__ __launch_bounds__(256) void gemm_presample(const f16x8* __restrict__ xh,
                                                      const f16x8* __restrict__ xl,
                                                      const f16x8* __restrict__ wh,
                                                      const f16x8* __restrict__ wl,
                                                      u32* __restrict__ thrbuf) {
  __shared__ f16x8 lds_raw[2048];            // 32 KB
  f16x8* AhV = lds_raw;
  f16x8* AlV = lds_raw + 512;
  f16x8* BhV = lds_raw + 1024;
  f16x8* BlV = lds_raw + 1536;

  const int id = blockIdx.x;                 // 256 blocks
  const int e0 = (id & 31) * BN;
  const int n  = (id >> 5) & 3;
  const int b  = id >> 7;

  const int tid  = threadIdx.x;
  const int lane = tid & 63;
  const int wid  = tid >> 6;
  const int wr   = wid >> 1;
  const int wc   = wid & 1;
  const int lm   = lane & 15;
  const int lk   = lane >> 4;

  f32x4 acc[4][4];
#pragma unroll
  for (int i = 0; i < 4; ++i)
#pragma unroll
    for (int j = 0; j < 4; ++j) acc[i][j] = (f32x4){0.f, 0.f, 0.f, 0.f};

  for (int k0 = 0; k0 < D_ / 8; k0 += 4) {
#pragma unroll
    for (int l = 0; l < 2; ++l) {
      int aid = tid + l * 256;
      int r   = aid >> 2;                    // 0..127 -> t = 32*r
      int ko  = aid & 3;
      int ps  = ko ^ ((r >> 1) & 3);
      size_t gA = ((size_t)(b * T_ + 32 * r) * NB_ + n) * (D_ / 8) + k0 + ko;
      AhV[r * 4 + ps] = xh[gA];
      AlV[r * 4 + ps] = xl[gA];
      size_t gB = ((size_t)n * E_ + e0 + r) * (D_ / 8) + k0 + ko;
      BhV[r * 4 + ps] = wh[gB];
      BlV[r * 4 + ps] = wl[gB];
    }
    __syncthreads();
    compute_step(lds_raw, acc, wr, wc, lm, lk);
    __syncthreads();
  }
  u64* ldsK = (u64*)lds_raw;                 // repurposed: [4][64][3] u64

#pragma unroll
  for (int fn = 0; fn < 4; ++fn) {
    const int e  = e0 + wc * 64 + fn * 16 + lm;
    const int ne = n * E_ + e;
    u32 v0 = 0, v1 = 0, v2 = 0;
    u32 tt0 = 0, tt1 = 0, tt2 = 0;
    const u32 ibase = (u32)b * HALF_ + (u32)ne;
#pragma unroll
    for (int fm = 0; fm < 4; ++fm) {
#pragma unroll
      for (int r = 0; r < 4; ++r) {
        const u32 t = 32u * (u32)(wr * 64 + fm * 16 + lk * 4 + r);
        float lg = acc[fm][fn][r] * INV_SC;
        u32 mu = __float_as_uint(fmaxf(lg, 0.0f)) | 0x80000000u;
        if (mu > v2) {                        // same rejection as strict-> insert
          float y = lg * noise_at(ibase + t * (u32)NE_);
          u32 mv = map_f32(y);
          bool g0 = mv > v0, g1 = mv > v1, g2 = mv > v2;
          v2  = g1 ? v1  : (g2 ? mv : v2);
          tt2 = g1 ? tt1 : (g2 ? t  : tt2);
          v1  = g0 ? v0  : (g1 ? mv : v1);
          tt1 = g0 ? tt0 : (g1 ? t  : tt1);
          v0  = g0 ? mv  : v0;
          tt0 = g0 ? t   : tt0;
        }
      }
    }
    u64 K0 = ((u64)v0 << 32) | (u64)(0xFFFFFFFFu - tt0);
    u64 K1 = ((u64)v1 << 32) | (u64)(0xFFFFFFFFu - tt1);
    u64 K2 = ((u64)v2 << 32) | (u64)(0xFFFFFFFFu - tt2);
    u64 p0 = __shfl_xor(K0, 16), p1 = __shfl_xor(K1, 16), p2 = __shfl_xor(K2, 16);
    merge3(K0, K1, K2, p0, p1, p2);
    p0 = __shfl_xor(K0, 32); p1 = __shfl_xor(K1, 32); p2 = __shfl_xor(K2, 32);
    merge3(K0, K1, K2, p0, p1, p2);
    if (lk == 0) {
      int c = fn * 16 + lm;
      ldsK[(wid * 64 + c) * 3 + 0] = K0;
      ldsK[(wid * 64 + c) * 3 + 1] = K1;
      ldsK[(wid * 64 + c) * 3 + 2] = K2;
    }
  }
  __syncthreads();
  if (wid < 2) {
    int c = lane;
    u64 A0 = ldsK[(wid * 64 + c) * 3 + 0];
    u64 A1 = ldsK[(wid * 64 + c) * 3 + 1];
    u64 A2 = ldsK[(wid * 64 + c) * 3 + 2];
    merge3(A0, A1, A2,
           ldsK[((wid + 2) * 64 + c) * 3 + 0],
           ldsK[((wid + 2) * 64 + c) * 3 + 1],
           ldsK[((wid + 2) * 64 + c) * 3 + 2]);
    int eg = e0 + wid * 64 + c;
    thrbuf[(size_t)b * NE_ + (size_t)n * E_ + eg] = (u32)(A2 >> 32);  // single writer
  }
}

// ---------------- Kernel 2: fused GEMM (2-phase dbuf + global_load_lds) + select ----------------
__global__ __launch_bounds__(256) void gemm_fused(const f16x8* __restrict__ xh,
                                                  const f16x8* __restrict__ xl,
                                                  const f16x8* __restrict__ wh,
                                                  const f16x8* __restrict__ wl,
                                                  float* __restrict__ logits,
                                                  u64* __restrict__ k0g,
                                                  u64* __restrict__ k1g,
                                                  u64* __restrict__ k2g,
                                                  u32* __restrict__ thrbuf) {
  __shared__ f16x8 lds_raw[4096];            // 64 KB: two 2048-slot K-tile buffers
  f16x8* bufA = lds_raw;
  f16x8* bufB = lds_raw + 2048;

  // decode: e0 fast / mt mid / n slow (R17)
  const int id = blockIdx.x;
  const int e0 = (id & 31) * BN;
  const int mt = (id >> 5) & 63;
  const int n  = id >> 11;
  const int m0 = mt * BM;                    // m = b*T + t

  const int tid  = threadIdx.x;
  const int lane = tid & 63;
  const int wid  = tid >> 6;                 // 4 waves: wid = wr*2 + wc
  const int wr   = wid >> 1;
  const int wc   = wid & 1;
  const int lm   = lane & 15;
  const int lk   = lane >> 4;                // k-group 0..3

  f32x4 acc[4][4];
#pragma unroll
  for (int i = 0; i < 4; ++i)
#pragma unroll
    for (int j = 0; j < 4; ++j) acc[i][j] = (f32x4){0.f, 0.f, 0.f, 0.f};

  // 2-phase pipeline: 16 K-steps (k0 = 4*kk), stage(next) issued BEFORE compute(cur)
  stage_tile(xh, xl, wh, wl, bufA, m0, n, e0, 0, wid, lane);
  __syncthreads();                           // drains vmcnt -> bufA ready
  for (int kk = 0; kk < 16; kk += 2) {
    stage_tile(xh, xl, wh, wl, bufB, m0, n, e0, 4 * (kk + 1), wid, lane);
    compute_step(bufA, acc, wr, wc, lm, lk);
    __syncthreads();                         // bufB ready; bufA reads done
    if (kk < 14)
      stage_tile(xh, xl, wh, wl, bufA, m0, n, e0, 4 * (kk + 2), wid, lane);
    compute_step(bufB, acc, wr, wc, lm, lk);
    __syncthreads();                         // bufA ready; bufB reads done
  }

  // LDS repurpose for epilogue:
  float* lgbuf = (float*)lds_raw;                    // 16 KB: [16 slots][256 threads]
  u16*   tbuf  = (u16*)((char*)lds_raw + 16384);     //  8 KB: [16 slots][256 threads]
  u64*   ldsK  = (u64*)((char*)lds_raw + 24576);     //  6 KB: [4 waves][64 cols][3]

  // ---- epilogue part 1: store logits (non-temporal: write-once stream,
  //      keeps the 96MB operand working set resident in L2/L3) ----
  const int b     = m0 >> 12;                // m0 / T_
  const int mbase = m0 & (T_ - 1);           // t of tile row 0
  const int mtile = mbase >> 7;

#pragma unroll
  for (int fm = 0; fm < 4; ++fm) {
#pragma unroll
    for (int r = 0; r < 4; ++r) {
      int m = m0 + wr * 64 + fm * 16 + lk * 4 + r;
      float* row = logits + ((size_t)m * NB_ + n) * E_ + e0 + wc * 64 + lm;
#pragma unroll
      for (int fn = 0; fn < 4; ++fn)
        __builtin_nontemporal_store(acc[fm][fn][r] * INV_SC, row + fn * 16);
    }
  }

  // ---- epilogue part 2: compacted pruned per-column noisy top-3 ----
#pragma unroll
  for (int fn = 0; fn < 4; ++fn) {
    const int e  = e0 + wc * 64 + fn * 16 + lm;   // e within [0,E)
    const int ne = n * E_ + e;
    const u32 thrv = thrbuf[(size_t)b * NE_ + ne];

    // pass 1: compact candidates (lg, t) into LDS
    int cnt = 0;
#pragma unroll
    for (int fm = 0; fm < 4; ++fm) {              // t ascends per lane
#pragma unroll
      for (int r = 0; r < 4; ++r) {
        float lg = acc[fm][fn][r] * INV_SC;
        u32 mu = __float_as_uint(fmaxf(lg, 0.0f)) | 0x80000000u;   // map(ub)
        if (mu >= thrv) {
          lgbuf[cnt * 256 + tid] = lg;
          tbuf [cnt * 256 + tid] = (u16)(mbase + wr * 64 + fm * 16 + lk * 4 + r);
          ++cnt;
        }
      }
    }

    // pass 2: evaluate candidates (wave runs max(cnt) iterations)
    u32 v0 = 0, v1 = 0, v2 = 0;
    u32 tt0 = 0, tt1 = 0, tt2 = 0;
    const u32 ibase = (u32)b * HALF_ + (u32)ne;
    for (int k = 0; k < cnt; ++k) {
      float lg = lgbuf[k * 256 + tid];
      u32 t    = (u32)tbuf[k * 256 + tid];
      float y  = lg * noise_at(ibase + t * (u32)NE_);
      u32 mv = map_f32(y);
      bool g0 = mv > v0, g1 = mv > v1, g2 = mv > v2;
      v2  = g1 ? v1  : (g2 ? mv : v2);
      tt2 = g1 ? tt1 : (g2 ? t  : tt2);
      v1  = g0 ? v0  : (g1 ? mv : v1);
      tt1 = g0 ? tt0 : (g1 ? t  : tt1);
      v0  = g0 ? mv  : v0;
      tt0 = g0 ? t   : tt0;
    }

    u64 K0 = ((u64)v0 << 32) | (u64)(0xFFFFFFFFu - tt0);
    u64 K1 = ((u64)v1 << 32) | (u64)(0xFFFFFFFFu - tt1);
    u64 K2 = ((u64)v2 << 32) | (u64)(0xFFFFFFFFu - tt2);
    // merge across the 4 lk-lanes of this lm-group
    u64 p0 = __shfl_xor(K0, 16), p1 = __shfl_xor(K1, 16), p2 = __shfl_xor(K2, 16);
    merge3(K0, K1, K2, p0, p1, p2);
    p0 = __shfl_xor(K0, 32); p1 = __shfl_xor(K1, 32); p2 = __shfl_xor(K2, 32);
    merge3(K0, K1, K2, p0, p1, p2);
    if (lk == 0) {
      int c = fn * 16 + lm;                  // 0..63
      ldsK[(wid * 64 + c) * 3 + 0] = K0;
      ldsK[(wid * 64 + c) * 3 + 1] = K1;
      ldsK[(wid * 64 + c) * 3 + 2] = K2;
    }
  }
  __syncthreads();
  if (wid < 2) {                             // wr==0 waves merge with their wr==1 partner
    int c = lane;                            // 0..63; e = e0 + wid*64 + c  (wid == wc here)
    u64 A0 = ldsK[(wid * 64 + c) * 3 + 0];
    u64 A1 = ldsK[(wid * 64 + c) * 3 + 1];
    u64 A2 = ldsK[(wid * 64 + c) * 3 + 2];
    u64 C0 = ldsK[((wid + 2) * 64 + c) * 3 + 0];
    u64 C1 = ldsK[((wid + 2) * 64 + c) * 3 + 1];
    u64 C2 = ldsK[((wid + 2) * 64 + c) * 3 + 2];
    merge3(A0, A1, A2, C0, C1, C2);
    int eg = e0 + wid * 64 + c;
    size_t R = (size_t)(mtile * 2 + b) * NE_ + (size_t)n * E_ + eg;
    __builtin_nontemporal_store(A0, k0g + R);
    __builtin_nontemporal_store(A1, k1g + R);
    __builtin_nontemporal_store(A2, k2g + R);
    // publish this tile's evaluated-subset 3rd-max as a prune threshold
    atomicMax(&thrbuf[(size_t)b * NE_ + (size_t)n * E_ + eg], (u32)(A2 >> 32));
  }
}

// ---------------- Kernel 3: merge tile records -> global top-3 -> slot scatter ----------------
__global__ __launch_bounds__(256) void merge_scatter2(const u64* __restrict__ k0g,
                                                      const u64* __restrict__ k1g,
                                                      const u64* __restrict__ k2g,
                                                      u64* __restrict__ keys) {
  int gid2 = blockIdx.x * 256 + threadIdx.x;  // 32768 = B*NB*E
  int b  = gid2 >> 14;
  int ne = gid2 & (NE_ - 1);

  u64 K0 = 0, K1 = 0, K2 = 0;
  for (int mt = 0; mt < MT_; ++mt) {
    size_t R = (size_t)(mt * 2 + b) * NE_ + ne;
    merge3(K0, K1, K2, k0g[R], k1g[R], k2g[R]);
  }

  int n = ne >> 12;
  u32 e = (u32)(ne & (E_ - 1));
  u64 elo = (u64)(0xFFFFFFFFu - e);
  u32 t0 = 0xFFFFFFFFu - (u32)K0;
  u32 t1 = 0xFFFFFFFFu - (u32)K1;
  u32 t2 = 0xFFFFFFFFu - (u32)K2;
  atomicMax(&keys[((size_t)b * T_ + t0) * NB_ + n], (K0 & 0xFFFFFFFF00000000ull) | elo);
  atomicMax(&keys[((size_t)b * T_ + t1) * NB_ + n], (K1 & 0xFFFFFFFF00000000ull) | elo);
  atomicMax(&keys[((size_t)b * T_ + t2) * NB_ + n], (K2 & 0xFFFFFFFF00000000ull) | elo);
}

// ---------------- Fallback path (small ws): in-kernel-split GEMM + monolithic select ----------------
__device__ __forceinline__ void split8(const float* __restrict__ p, f16x8 &hi, f16x8 &lo) {
  float4 a0 = *(const float4*)p;
  float4 a1 = *(const float4*)(p + 4);
  split8v(a0, a1, hi, lo);
}

__global__ __launch_bounds__(256) void gemm_logits_fb(const float* __restrict__ x,
                                                      const float* __restrict__ W,
                                                      float* __restrict__ logits) {
  __shared__ f16x8 lds_raw[2048];
  f16x8* AhV = lds_raw;
  f16x8* AlV = lds_raw + 512;
  f16x8* BhV = lds_raw + 1024;
  f16x8* BlV = lds_raw + 1536;

  const int n  = blockIdx.z;
  const int m0 = blockIdx.y * BM;
  const int e0 = blockIdx.x * BN;
  const int tid  = threadIdx.x;
  const int lane = tid & 63;
  const int wid  = tid >> 6;
  const int wr   = wid >> 1;
  const int wc   = wid & 1;
  const int lm   = lane & 15;
  const int lk   = lane >> 4;

  const float* Abase = x + ((size_t)m0 * NB_ + n) * D_;
  const float* Bbase = W + ((size_t)n * E_ + e0) * D_;

  f32x4 acc[4][4];
#pragma unroll
  for (int i = 0; i < 4; ++i)
#pragma unroll
    for (int j = 0; j < 4; ++j) acc[i][j] = (f32x4){0.f, 0.f, 0.f, 0.f};

  for (int k0 = 0; k0 < D_; k0 += 32) {
#pragma unroll
    for (int l = 0; l < 2; ++l) {
      int aid = tid + l * 256;
      int r   = aid >> 2;
      int ko  = aid & 3;
      int ps  = ko ^ ((r >> 1) & 3);
      f16x8 hi, lo;
      split8(Abase + (size_t)r * (NB_ * D_) + k0 + ko * 8, hi, lo);
      AhV[r * 4 + ps] = hi; AlV[r * 4 + ps] = lo;
      split8(Bbase + (size_t)r * D_ + k0 + ko * 8, hi, lo);
      BhV[r * 4 + ps] = hi; BlV[r * 4 + ps] = lo;
    }
    __syncthreads();
    compute_step(lds_raw, acc, wr, wc, lm, lk);
    __syncthreads();
  }

#pragma unroll
  for (int fm = 0; fm < 4; ++fm) {
#pragma unroll
    for (int fn = 0; fn < 4; ++fn) {
#pragma unroll
      for (int r = 0; r < 4; ++r) {
        int m = m0 + wr * 64 + fm * 16 + lk * 4 + r;
        int e = e0 + wc * 64 + fn * 16 + lm;
        logits[((size_t)m * NB_ + n) * E_ + e] = acc[fm][fn][r] * INV_SC;
      }
    }
  }
}

__global__ __launch_bounds__(256) void select_scatter(const float* __restrict__ logits,
                                                      u64* __restrict__ keys) {
  int gid = blockIdx.x * 256 + threadIdx.x;  // 32768 = B*NB*E
  int b  = gid >> 14;
  int ne = gid & (NE_ - 1);

  float v0 = -1e30f, v1 = -1e30f, v2 = -1e30f;
  int   t0 = 0, t1 = 0, t2 = 0;

  const float* lg = logits + (size_t)b * HALF_;
  const u32 ib = (u32)b * HALF_ + (u32)ne;
  for (int t = 0; t < T_; ++t) {
    u32 i0 = (u32)t * (u32)NE_ + (u32)ne;
    float y = lg[i0] * noise_at(ib + (u32)t * (u32)NE_);
    if (y > v0)      { v2=v1; t2=t1; v1=v0; t1=t0; v0=y; t0=t; }
    else if (y > v1) { v2=v1; t2=t1; v1=y;  t1=t; }
    else if (y > v2) { v2=y;  t2=t; }
  }

  int n = ne >> 12;
  int e = ne & (E_ - 1);
  u64 klo = 0xFFFFFFFFull - (u32)e;
  atomicMax(&keys[((size_t)b * T_ + t0) * NB_ + n], ((u64)map_f32(v0) << 32) | klo);
  atomicMax(&keys[((size_t)b * T_ + t1) * NB_ + n], ((u64)map_f32(v1) << 32) | klo);
  atomicMax(&keys[((size_t)b * T_ + t2) * NB_ + n], ((u64)map_f32(v2) << 32) | klo);
}

// ---------------- Kernel 4: decode argmax -> idx + latent gather ----------------
__global__ __launch_bounds__(128) void finalize(const u64* __restrict__ keys,
                                                const float* __restrict__ W,
                                                float* __restrict__ out_idx,
                                                float* __restrict__ out_lat) {
  int slot = blockIdx.x;                     // (b*T+t)*NB + n
  int n = slot & (NB_ - 1);
  int e = (int)(0xFFFFFFFFu - (u32)keys[slot]) & (E_ - 1);
  if (threadIdx.x == 0) out_idx[slot] = (float)e;

  const float4 v = ((const float4*)(W + ((size_t)n * E_ + e) * D_))[threadIdx.x];
  ((float4*)(out_lat + (size_t)slot * D_))[threadIdx.x] = v;   // 128 x 16B = 2KB
}

// ---------------- Launch ----------------
extern "C" void kernel_launch(void* const* d_in, const int* in_sizes, int n_in,
                              void* d_out, int out_size, void* d_ws, size_t ws_size,
                              hipStream_t stream) {
  const float* x = (const float*)d_in[0];    // [B,T,NB*D] fp32
  const float* W = (const float*)d_in[1];    // [NB,E,D]  fp32

  float* out_idx    = (float*)d_out;                          // 32,768
  float* out_lat    = out_idx + (size_t)SLOTS_;               // 16,777,216
  float* out_logits = out_lat + (size_t)SLOTS_ * D_;          // 134,217,728

  // ws layout: keys | thr | xh | xl | wh | wl
  u64* keys = (u64*)d_ws;
  const size_t KEYS_B = (size_t)SLOTS_ * 8;                   // 256 KiB
  const size_t THR_B  = (size_t)SLOTS_ * 4;                   // 128 KiB
  const size_t XH_B   = (size_t)XN8_ * 16;                    // 32 MiB
  const size_t WH_B   = (size_t)WN8_ * 16;                    // 16 MiB
  bool split = ws_size >= KEYS_B + THR_B + 2 * XH_B + 2 * WH_B;

  u32*   thr = (u32*)((char*)d_ws + KEYS_B);
  char*  sp  = (char*)d_ws + KEYS_B + THR_B;
  f16x8* xh  = (f16x8*)sp;
  f16x8* xl  = (f16x8*)(sp + XH_B);
  f16x8* wh  = (f16x8*)(sp + 2 * XH_B);
  f16x8* wl  = (f16x8*)(sp + 2 * XH_B + WH_B);

  // tile-select records live in the out_lat region (overwritten by finalize later)
  u64* k0g = (u64*)out_lat;                                   // 8 MB each
  u64* k1g = k0g + RECN_;
  u64* k2g = k1g + RECN_;

  init_keys<<<SLOTS_ / 256, 256, 0, stream>>>(keys, thr);

  if (split) {
    presplit<<<(XN8_ + WN8_) / 256, 256, 0, stream>>>(x, W, xh, xl, wh, wl);
    gemm_presample<<<256, 256, 0, stream>>>(xh, xl, wh, wl, thr);
    gemm_fused<<<8192, 256, 0, stream>>>(xh, xl, wh, wl, out_logits, k0g, k1g, k2g, thr);
    merge_scatter2<<<SLOTS_ / 256, 256, 0, stream>>>(k0g, k1g, k2g, keys);
  } else {
    dim3 ggrid(E_ / BN, (B_ * T_) / BM, NB_);
    gemm_logits_fb<<<ggrid, 256, 0, stream>>>(x, W, out_logits);
    select_scatter<<<SLOTS_ / 256, 256, 0, stream>>>(out_logits, keys);
  }

  finalize<<<SLOTS_, 128, 0, stream>>>(keys, W, out_idx, out_lat);
}

// Round 20
// 579.797 us; speedup vs baseline: 1.2719x; 1.0547x over previous
//
#include <hip/hip_runtime.h>
#include <stdint.h>

// Problem constants
#define B_     2
#define T_     4096
#define NB_    4
#define D_     512
#define E_     4096
#define NE_    16384           // NB*E
#define HALF_  67108864u       // T*NB*E  (per-b flat block of [B,T,NB,E])
#define SLOTS_ 32768           // B*T*NB
#define XN8_   2097152         // B*T*NB*D/8
#define WN8_   1048576         // NB*E*D/8
#define MT_    32              // m-tiles per b = T/128
#define RECN_  (64 * NE_)      // (MT_*B) * NE records per key array

typedef unsigned long long u64;
typedef uint32_t u32;
typedef uint16_t u16;
typedef _Float16 f16x8 __attribute__((ext_vector_type(8)));
typedef float    f32x4 __attribute__((ext_vector_type(4)));

// async global->LDS, 16B per lane; LDS dest wave-uniform base + lane*16
#define GLD(srcp, dstp) __builtin_amdgcn_global_load_lds( \
    (const __attribute__((address_space(1))) void*)(srcp), \
    (__attribute__((address_space(3))) void*)(dstp), 16, 0, 0)

// ---------------- Threefry-2x32-20, key = (0, 42) ----------------
__device__ __forceinline__ u32 rotl32(u32 x, int r) { return __builtin_rotateleft32(x, r); }

__device__ __forceinline__ void tf_0_42(u32 x0, u32 x1, u32 &o0, u32 &o1) {
  const u32 ks0 = 0u, ks1 = 42u, ks2 = 0x1BD11BDAu ^ 0u ^ 42u;
  x0 += ks0; x1 += ks1;
#define TFR(r) { x0 += x1; x1 = rotl32(x1, (r)); x1 ^= x0; }
  TFR(13) TFR(15) TFR(26) TFR(6)
  x0 += ks1; x1 += ks2 + 1u;
  TFR(17) TFR(29) TFR(16) TFR(24)
  x0 += ks2; x1 += ks0 + 2u;
  TFR(13) TFR(15) TFR(26) TFR(6)
  x0 += ks0; x1 += ks1 + 3u;
  TFR(17) TFR(29) TFR(16) TFR(24)
  x0 += ks1; x1 += ks2 + 4u;
  TFR(13) TFR(15) TFR(26) TFR(6)
  x0 += ks2; x1 += ks0 + 5u;
#undef TFR
  o0 = x0; o1 = x1;
}

// Partitionable noise (VERIFIED R7): XOR fold o0^o1 of threefry(key,(0,i))
__device__ __forceinline__ float noise_at(u32 i) {
  u32 o0, o1; tf_0_42(0u, i, o0, o1);
  u32 bits = o0 ^ o1;
  float f = __uint_as_float((bits >> 9) | 0x3F800000u);  // [1,2)
  return 2.0f - f;                                        // 1 - uniform
}

// order-preserving map fp32 -> u32, branchless (finite inputs)
__device__ __forceinline__ u32 map_f32(float v) {
  u32 u = __float_as_uint(v);
  u32 s = (u32)((int)u >> 31);               // 0 or 0xFFFFFFFF
  return u ^ (s | 0x80000000u);
}

// merge two sorted-desc key triples: (a0>=a1>=a2) <- top3 of {a*, b*}
__device__ __forceinline__ void merge3(u64 &a0, u64 &a1, u64 &a2,
                                       u64 b0, u64 b1, u64 b2) {
  u64 o0, o1, o2;
  if (a0 >= b0) {
    o0 = a0;
    if (a1 >= b0) { o1 = a1; o2 = (a2 >= b0) ? a2 : b0; }
    else          { o1 = b0; o2 = (a1 >= b1) ? a1 : b1; }
  } else {
    o0 = b0;
    if (b1 >= a0) { o1 = b1; o2 = (b2 >= a0) ? b2 : a0; }
    else          { o1 = a0; o2 = (b1 >= a1) ? b1 : a1; }
  }
  a0 = o0; a1 = o1; a2 = o2;
}

#define BASE_KEY 0x80000000FFFFFFFFull   // (+0.0, e=0): empty slot -> argmax 0
#define SCALE_   2048.0f
#define INV_SC   (1.0f / 4194304.0f)     // 2^-22

// ---------------- Kernel 1: init keys + prune thresholds ----------------
__global__ __launch_bounds__(256) void init_keys(u64* __restrict__ keys,
                                                 u32* __restrict__ thr) {
  int i = blockIdx.x * 256 + threadIdx.x;    // 32768
  keys[i] = BASE_KEY;
  thr[i]  = 0u;
}

// ---------------- Kernel 1b: pre-split fp32 -> (hi,lo) fp16, scaled by 2^11 ----------------
__device__ __forceinline__ void split8v(const float4 a0, const float4 a1, f16x8 &hi, f16x8 &lo) {
  float fv[8] = {a0.x, a0.y, a0.z, a0.w, a1.x, a1.y, a1.z, a1.w};
#pragma unroll
  for (int j = 0; j < 8; ++j) {
    float f = fv[j] * SCALE_;
    _Float16 h = (_Float16)f;
    hi[j] = h;
    lo[j] = (_Float16)(f - (float)h);
  }
}

__global__ __launch_bounds__(256) void presplit(const float* __restrict__ x,
                                                const float* __restrict__ W,
                                                f16x8* __restrict__ xh, f16x8* __restrict__ xl,
                                                f16x8* __restrict__ wh, f16x8* __restrict__ wl) {
  size_t g = (size_t)blockIdx.x * 256 + threadIdx.x;   // unit = 8 floats
  const float4* src;
  f16x8 *dh, *dl;
  size_t off;
  if (g < XN8_) { src = (const float4*)x; dh = xh; dl = xl; off = g; }
  else          { src = (const float4*)W; dh = wh; dl = wl; off = g - XN8_; }
  float4 a0 = src[off * 2], a1 = src[off * 2 + 1];
  f16x8 hi, lo;
  split8v(a0, a1, hi, lo);
  dh[off] = hi; dl[off] = lo;
}

// ---------------- shared GEMM helpers ----------------
#define BM 128
#define BN 128

// 4-wave helpers (presample / fallback, 256 threads)
__device__ __forceinline__ void compute_step(const f16x8* buf, f32x4 acc[4][4],
                                             int wr, int wc, int lm, int lk) {
  const f16x8* Ah = buf;
  const f16x8* Al = buf + 512;
  const f16x8* Bh = buf + 1024;
  const f16x8* Bl = buf + 1536;
  f16x8 bh[4], bl[4];
#pragma unroll
  for (int fn = 0; fn < 4; ++fn) {
    int row = wc * 64 + fn * 16 + lm;
    int ps  = lk ^ ((row >> 1) & 3);
    bh[fn] = Bh[row * 4 + ps];
    bl[fn] = Bl[row * 4 + ps];
  }
#pragma unroll
  for (int fm = 0; fm < 4; ++fm) {
    int row = wr * 64 + fm * 16 + lm;
    int ps  = lk ^ ((row >> 1) & 3);
    f16x8 ah = Ah[row * 4 + ps];
    f16x8 al = Al[row * 4 + ps];
#pragma unroll
    for (int fn = 0; fn < 4; ++fn) {
      acc[fm][fn] = __builtin_amdgcn_mfma_f32_16x16x32_f16(ah, bh[fn], acc[fm][fn], 0, 0, 0);
      acc[fm][fn] = __builtin_amdgcn_mfma_f32_16x16x32_f16(ah, bl[fn], acc[fm][fn], 0, 0, 0);
      acc[fm][fn] = __builtin_amdgcn_mfma_f32_16x16x32_f16(al, bh[fn], acc[fm][fn], 0, 0, 0);
    }
  }
}

// 8-wave helpers (gemm_fused, 512 threads)
__device__ __forceinline__ void stage_tile8(const f16x8* __restrict__ xh,
                                            const f16x8* __restrict__ xl,
                                            const f16x8* __restrict__ wh,
                                            const f16x8* __restrict__ wl,
                                            f16x8* buf, int m0, int n, int e0,
                                            int k0, int w, int lane) {
  int sbase = w * 64;                        // wave-uniform slot base (8 waves x 64)
  int s  = sbase + lane;                     // 0..511
  int r  = s >> 2;                           // tile row
  int ko = (s & 3) ^ ((r >> 1) & 3);         // pre-swizzled source k-group
  size_t gA = ((size_t)(m0 + r) * NB_ + n) * (D_ / 8) + k0 + ko;
  size_t gB = ((size_t)n * E_ + e0 + r) * (D_ / 8) + k0 + ko;
  GLD(xh + gA, buf + sbase);
  GLD(xl + gA, buf + 512 + sbase);
  GLD(wh + gB, buf + 1024 + sbase);
  GLD(wl + gB, buf + 1536 + sbase);
}

__device__ __forceinline__ void compute_step8(const f16x8* buf, f32x4 acc[4][2],
                                              int wr, int wc, int lm, int lk) {
  const f16x8* Ah = buf;
  const f16x8* Al = buf + 512;
  const f16x8* Bh = buf + 1024;
  const f16x8* Bl = buf + 1536;
  f16x8 bh[2], bl[2];
#pragma unroll
  for (int fn = 0; fn < 2; ++fn) {
    int row = wc * 32 + fn * 16 + lm;
    int ps  = lk ^ ((row >> 1) & 3);
    bh[fn] = Bh[row * 4 + ps];
    bl[fn] = Bl[row * 4 + ps];
  }
#pragma unroll
  for (int fm = 0; fm < 4; ++fm) {
    int row = wr * 64 + fm * 16 + lm;
    int ps  = lk ^ ((row >> 1) & 3);
    f16x8 ah = Ah[row * 4 + ps];
    f16x8 al = Al[row * 4 + ps];
#pragma unroll
    for (int fn = 0; fn < 2; ++fn) {
      acc[fm][fn] = __builtin_amdgcn_mfma_f32_16x16x32_f16(ah, bh[fn], acc[fm][fn], 0, 0, 0);
      acc[fm][fn] = __builtin_amdgcn_mfma_f32_16x16x32_f16(ah, bl[fn], acc[fm][fn], 0, 0, 0);
      acc[fm][fn] = __builtin_amdgcn_mfma_f32_16x16x32_f16(al, bh[fn], acc[fm][fn], 0, 0, 0);
    }
  }
}

// ---------------- Kernel 1c: presample pre-warm (t = 32*k sampled rows) ----------------
__global__ __launch_bounds__(256) void gemm_presample(const f16x8* __restrict__ xh,
                                                      const f16x8* __restrict__ xl,
                                                      const f16x8* __restrict__ wh,
                                                      const f16x8* __restrict__ wl,
                                                      u32* __restrict__ thrbuf) {
  __shared__ f16x8 lds_raw[2048];            // 32 KB
  f16x8* AhV = lds_raw;
  f16x8* AlV = lds_raw + 512;
  f16x8* BhV = lds_raw + 1024;
  f16x8* BlV = lds_raw + 1536;

  const int id = blockIdx.x;                 // 256 blocks
  const int e0 = (id & 31) * BN;
  const int n  = (id >> 5) & 3;
  const int b  = id >> 7;

  const int tid  = threadIdx.x;
  const int lane = tid & 63;
  const int wid  = tid >> 6;
  const int wr   = wid >> 1;
  const int wc   = wid & 1;
  const int lm   = lane & 15;
  const int lk   = lane >> 4;

  f32x4 acc[4][4];
#pragma unroll
  for (int i = 0; i < 4; ++i)
#pragma unroll
    for (int j = 0; j < 4; ++j) acc[i][j] = (f32x4){0.f, 0.f, 0.f, 0.f};

  for (int k0 = 0; k0 < D_ / 8; k0 += 4) {
#pragma unroll
    for (int l = 0; l < 2; ++l) {
      int aid = tid + l * 256;
      int r   = aid >> 2;                    // 0..127 -> t = 32*r
      int ko  = aid & 3;
      int ps  = ko ^ ((r >> 1) & 3);
      size_t gA = ((size_t)(b * T_ + 32 * r) * NB_ + n) * (D_ / 8) + k0 + ko;
      AhV[r * 4 + ps] = xh[gA];
      AlV[r * 4 + ps] = xl[gA];
      size_t gB = ((size_t)n * E_ + e0 + r) * (D_ / 8) + k0 + ko;
      BhV[r * 4 + ps] = wh[gB];
      BlV[r * 4 + ps] = wl[gB];
    }
    __syncthreads();
    compute_step(lds_raw, acc, wr, wc, lm, lk);
    __syncthreads();
  }
  u64* ldsK = (u64*)lds_raw;                 // repurposed: [4][64][3] u64

#pragma unroll
  for (int fn = 0; fn < 4; ++fn) {
    const int e  = e0 + wc * 64 + fn * 16 + lm;
    const int ne = n * E_ + e;
    u32 v0 = 0, v1 = 0, v2 = 0;
    u32 tt0 = 0, tt1 = 0, tt2 = 0;
    const u32 ibase = (u32)b * HALF_ + (u32)ne;
#pragma unroll
    for (int fm = 0; fm < 4; ++fm) {
#pragma unroll
      for (int r = 0; r < 4; ++r) {
        const u32 t = 32u * (u32)(wr * 64 + fm * 16 + lk * 4 + r);
        float lg = acc[fm][fn][r] * INV_SC;
        u32 mu = __float_as_uint(fmaxf(lg, 0.0f)) | 0x80000000u;
        if (mu > v2) {                        // same rejection as strict-> insert
          float y = lg * noise_at(ibase + t * (u32)NE_);
          u32 mv = map_f32(y);
          bool g0 = mv > v0, g1 = mv > v1, g2 = mv > v2;
          v2  = g1 ? v1  : (g2 ? mv : v2);
          tt2 = g1 ? tt1 : (g2 ? t  : tt2);
          v1  = g0 ? v0  : (g1 ? mv : v1);
          tt1 = g0 ? tt0 : (g1 ? t  : tt1);
          v0  = g0 ? mv  : v0;
          tt0 = g0 ? t   : tt0;
        }
      }
    }
    u64 K0 = ((u64)v0 << 32) | (u64)(0xFFFFFFFFu - tt0);
    u64 K1 = ((u64)v1 << 32) | (u64)(0xFFFFFFFFu - tt1);
    u64 K2 = ((u64)v2 << 32) | (u64)(0xFFFFFFFFu - tt2);
    u64 p0 = __shfl_xor(K0, 16), p1 = __shfl_xor(K1, 16), p2 = __shfl_xor(K2, 16);
    merge3(K0, K1, K2, p0, p1, p2);
    p0 = __shfl_xor(K0, 32); p1 = __shfl_xor(K1, 32); p2 = __shfl_xor(K2, 32);
    merge3(K0, K1, K2, p0, p1, p2);
    if (lk == 0) {
      int c = fn * 16 + lm;
      ldsK[(wid * 64 + c) * 3 + 0] = K0;
      ldsK[(wid * 64 + c) * 3 + 1] = K1;
      ldsK[(wid * 64 + c) * 3 + 2] = K2;
    }
  }
  __syncthreads();
  if (wid < 2) {
    int c = lane;
    u64 A0 = ldsK[(wid * 64 + c) * 3 + 0];
    u64 A1 = ldsK[(wid * 64 + c) * 3 + 1];
    u64 A2 = ldsK[(wid * 64 + c) * 3 + 2];
    merge3(A0, A1, A2,
           ldsK[((wid + 2) * 64 + c) * 3 + 0],
           ldsK[((wid + 2) * 64 + c) * 3 + 1],
           ldsK[((wid + 2) * 64 + c) * 3 + 2]);
    int eg = e0 + wid * 64 + c;
    thrbuf[(size_t)b * NE_ + (size_t)n * E_ + eg] = (u32)(A2 >> 32);  // single writer
  }
}

// ---------------- Kernel 2: fused GEMM (8 waves, 2-phase dbuf + global_load_lds) ----------------
__global__ __launch_bounds__(512, 4) void gemm_fused(const f16x8* __restrict__ xh,
                                                     const f16x8* __restrict__ xl,
                                                     const f16x8* __restrict__ wh,
                                                     const f16x8* __restrict__ wl,
                                                     float* __restrict__ logits,
                                                     u64* __restrict__ k0g,
                                                     u64* __restrict__ k1g,
                                                     u64* __restrict__ k2g,
                                                     u32* __restrict__ thrbuf) {
  __shared__ f16x8 lds_raw[4096];            // 64 KB: two 2048-slot K-tile buffers
  f16x8* bufA = lds_raw;
  f16x8* bufB = lds_raw + 2048;

  // decode: e0 fast / mt mid / n slow (R17)
  const int id = blockIdx.x;
  const int e0 = (id & 31) * BN;
  const int mt = (id >> 5) & 63;
  const int n  = id >> 11;
  const int m0 = mt * BM;                    // m = b*T + t

  const int tid  = threadIdx.x;
  const int lane = tid & 63;
  const int wid  = tid >> 6;                 // 8 waves: wid = wr*4 + wc
  const int wr   = wid >> 2;                 // 0..1 (m-half)
  const int wc   = wid & 3;                  // 0..3 (e-quarter)
  const int lm   = lane & 15;
  const int lk   = lane >> 4;                // k-group 0..3

  f32x4 acc[4][2];
#pragma unroll
  for (int i = 0; i < 4; ++i)
#pragma unroll
    for (int j = 0; j < 2; ++j) acc[i][j] = (f32x4){0.f, 0.f, 0.f, 0.f};

  // 2-phase pipeline: 16 K-steps, stage(next) issued BEFORE compute(cur)
  stage_tile8(xh, xl, wh, wl, bufA, m0, n, e0, 0, wid, lane);
  __syncthreads();
  for (int kk = 0; kk < 16; kk += 2) {
    stage_tile8(xh, xl, wh, wl, bufB, m0, n, e0, 4 * (kk + 1), wid, lane);
    compute_step8(bufA, acc, wr, wc, lm, lk);
    __syncthreads();
    if (kk < 14)
      stage_tile8(xh, xl, wh, wl, bufA, m0, n, e0, 4 * (kk + 2), wid, lane);
    compute_step8(bufB, acc, wr, wc, lm, lk);
    __syncthreads();
  }

  // LDS repurpose for epilogue:
  float* lgbuf = (float*)lds_raw;                    // 32 KB: [16 slots][512 threads]
  u16*   tbuf  = (u16*)((char*)lds_raw + 32768);     // 16 KB: [16 slots][512 threads]
  u64*   ldsK  = (u64*)((char*)lds_raw + 49152);     //  6 KB: [8 waves][32 cols][3]

  // ---- epilogue part 1: store logits (non-temporal write-once stream) ----
  const int b     = m0 >> 12;                // m0 / T_
  const int mbase = m0 & (T_ - 1);           // t of tile row 0
  const int mtile = mbase >> 7;

#pragma unroll
  for (int fm = 0; fm < 4; ++fm) {
#pragma unroll
    for (int r = 0; r < 4; ++r) {
      int m = m0 + wr * 64 + fm * 16 + lk * 4 + r;
      float* row = logits + ((size_t)m * NB_ + n) * E_ + e0 + wc * 32 + lm;
#pragma unroll
      for (int fn = 0; fn < 2; ++fn)
        __builtin_nontemporal_store(acc[fm][fn][r] * INV_SC, row + fn * 16);
    }
  }

  // ---- epilogue part 2: compacted pruned per-column noisy top-3 ----
#pragma unroll
  for (int fn = 0; fn < 2; ++fn) {
    const int e  = e0 + wc * 32 + fn * 16 + lm;   // e within [0,E)
    const int ne = n * E_ + e;
    const u32 thrv = thrbuf[(size_t)b * NE_ + ne];

    // pass 1: compact candidates (lg, t) into LDS
    int cnt = 0;
#pragma unroll
    for (int fm = 0; fm < 4; ++fm) {              // t ascends per lane
#pragma unroll
      for (int r = 0; r < 4; ++r) {
        float lg = acc[fm][fn][r] * INV_SC;
        u32 mu = __float_as_uint(fmaxf(lg, 0.0f)) | 0x80000000u;   // map(ub)
        if (mu >= thrv) {
          lgbuf[cnt * 512 + tid] = lg;
          tbuf [cnt * 512 + tid] = (u16)(mbase + wr * 64 + fm * 16 + lk * 4 + r);
          ++cnt;
        }
      }
    }

    // pass 2: evaluate candidates (wave runs max(cnt) iterations)
    u32 v0 = 0, v1 = 0, v2 = 0;
    u32 tt0 = 0, tt1 = 0, tt2 = 0;
    const u32 ibase = (u32)b * HALF_ + (u32)ne;
    for (int k = 0; k < cnt; ++k) {
      float lg = lgbuf[k * 512 + tid];
      u32 t    = (u32)tbuf[k * 512 + tid];
      float y  = lg * noise_at(ibase + t * (u32)NE_);
      u32 mv = map_f32(y);
      bool g0 = mv > v0, g1 = mv > v1, g2 = mv > v2;
      v2  = g1 ? v1  : (g2 ? mv : v2);
      tt2 = g1 ? tt1 : (g2 ? t  : tt2);
      v1  = g0 ? v0  : (g1 ? mv : v1);
      tt1 = g0 ? tt0 : (g1 ? t  : tt1);
      v0  = g0 ? mv  : v0;
      tt0 = g0 ? t   : tt0;
    }

    u64 K0 = ((u64)v0 << 32) | (u64)(0xFFFFFFFFu - tt0);
    u64 K1 = ((u64)v1 << 32) | (u64)(0xFFFFFFFFu - tt1);
    u64 K2 = ((u64)v2 << 32) | (u64)(0xFFFFFFFFu - tt2);
    // merge across the 4 lk-lanes of this lm-group
    u64 p0 = __shfl_xor(K0, 16), p1 = __shfl_xor(K1, 16), p2 = __shfl_xor(K2, 16);
    merge3(K0, K1, K2, p0, p1, p2);
    p0 = __shfl_xor(K0, 32); p1 = __shfl_xor(K1, 32); p2 = __shfl_xor(K2, 32);
    merge3(K0, K1, K2, p0, p1, p2);
    if (lk == 0) {
      int c = fn * 16 + lm;                  // 0..31
      ldsK[(wid * 32 + c) * 3 + 0] = K0;
      ldsK[(wid * 32 + c) * 3 + 1] = K1;
      ldsK[(wid * 32 + c) * 3 + 2] = K2;
    }
  }
  __syncthreads();
  if (wid < 4 && lane < 32) {                // wr==0 waves merge with wr==1 partner (wid+4)
    int c = lane;                            // 0..31; wc == wid here
    u64 A0 = ldsK[(wid * 32 + c) * 3 + 0];
    u64 A1 = ldsK[(wid * 32 + c) * 3 + 1];
    u64 A2 = ldsK[(wid * 32 + c) * 3 + 2];
    u64 C0 = ldsK[((wid + 4) * 32 + c) * 3 + 0];
    u64 C1 = ldsK[((wid + 4) * 32 + c) * 3 + 1];
    u64 C2 = ldsK[((wid + 4) * 32 + c) * 3 + 2];
    merge3(A0, A1, A2, C0, C1, C2);
    int eg = e0 + wid * 32 + c;
    size_t R = (size_t)(mtile * 2 + b) * NE_ + (size_t)n * E_ + eg;
    __builtin_nontemporal_store(A0, k0g + R);
    __builtin_nontemporal_store(A1, k1g + R);
    __builtin_nontemporal_store(A2, k2g + R);
    // publish this tile's evaluated-subset 3rd-max as a prune threshold
    atomicMax(&thrbuf[(size_t)b * NE_ + (size_t)n * E_ + eg], (u32)(A2 >> 32));
  }
}

// ---------------- Kernel 3: merge tile records -> global top-3 -> slot scatter ----------------
__global__ __launch_bounds__(256) void merge_scatter2(const u64* __restrict__ k0g,
                                                      const u64* __restrict__ k1g,
                                                      const u64* __restrict__ k2g,
                                                      u64* __restrict__ keys) {
  int gid2 = blockIdx.x * 256 + threadIdx.x;  // 32768 = B*NB*E
  int b  = gid2 >> 14;
  int ne = gid2 & (NE_ - 1);

  u64 K0 = 0, K1 = 0, K2 = 0;
  for (int mt = 0; mt < MT_; ++mt) {
    size_t R = (size_t)(mt * 2 + b) * NE_ + ne;
    merge3(K0, K1, K2, k0g[R], k1g[R], k2g[R]);
  }

  int n = ne >> 12;
  u32 e = (u32)(ne & (E_ - 1));
  u64 elo = (u64)(0xFFFFFFFFu - e);
  u32 t0 = 0xFFFFFFFFu - (u32)K0;
  u32 t1 = 0xFFFFFFFFu - (u32)K1;
  u32 t2 = 0xFFFFFFFFu - (u32)K2;
  atomicMax(&keys[((size_t)b * T_ + t0) * NB_ + n], (K0 & 0xFFFFFFFF00000000ull) | elo);
  atomicMax(&keys[((size_t)b * T_ + t1) * NB_ + n], (K1 & 0xFFFFFFFF00000000ull) | elo);
  atomicMax(&keys[((size_t)b * T_ + t2) * NB_ + n], (K2 & 0xFFFFFFFF00000000ull) | elo);
}

// ---------------- Fallback path (small ws): in-kernel-split GEMM + monolithic select ----------------
__device__ __forceinline__ void split8(const float* __restrict__ p, f16x8 &hi, f16x8 &lo) {
  float4 a0 = *(const float4*)p;
  float4 a1 = *(const float4*)(p + 4);
  split8v(a0, a1, hi, lo);
}

__global__ __launch_bounds__(256) void gemm_logits_fb(const float* __restrict__ x,
                                                      const float* __restrict__ W,
                                                      float* __restrict__ logits) {
  __shared__ f16x8 lds_raw[2048];
  f16x8* AhV = lds_raw;
  f16x8* AlV = lds_raw + 512;
  f16x8* BhV = lds_raw + 1024;
  f16x8* BlV = lds_raw + 1536;

  const int n  = blockIdx.z;
  const int m0 = blockIdx.y * BM;
  const int e0 = blockIdx.x * BN;
  const int tid  = threadIdx.x;
  const int lane = tid & 63;
  const int wid  = tid >> 6;
  const int wr   = wid >> 1;
  const int wc   = wid & 1;
  const int lm   = lane & 15;
  const int lk   = lane >> 4;

  const float* Abase = x + ((size_t)m0 * NB_ + n) * D_;
  const float* Bbase = W + ((size_t)n * E_ + e0) * D_;

  f32x4 acc[4][4];
#pragma unroll
  for (int i = 0; i < 4; ++i)
#pragma unroll
    for (int j = 0; j < 4; ++j) acc[i][j] = (f32x4){0.f, 0.f, 0.f, 0.f};

  for (int k0 = 0; k0 < D_; k0 += 32) {
#pragma unroll
    for (int l = 0; l < 2; ++l) {
      int aid = tid + l * 256;
      int r   = aid >> 2;
      int ko  = aid & 3;
      int ps  = ko ^ ((r >> 1) & 3);
      f16x8 hi, lo;
      split8(Abase + (size_t)r * (NB_ * D_) + k0 + ko * 8, hi, lo);
      AhV[r * 4 + ps] = hi; AlV[r * 4 + ps] = lo;
      split8(Bbase + (size_t)r * D_ + k0 + ko * 8, hi, lo);
      BhV[r * 4 + ps] = hi; BlV[r * 4 + ps] = lo;
    }
    __syncthreads();
    compute_step(lds_raw, acc, wr, wc, lm, lk);
    __syncthreads();
  }

#pragma unroll
  for (int fm = 0; fm < 4; ++fm) {
#pragma unroll
    for (int fn = 0; fn < 4; ++fn) {
#pragma unroll
      for (int r = 0; r < 4; ++r) {
        int m = m0 + wr * 64 + fm * 16 + lk * 4 + r;
        int e = e0 + wc * 64 + fn * 16 + lm;
        logits[((size_t)m * NB_ + n) * E_ + e] = acc[fm][fn][r] * INV_SC;
      }
    }
  }
}

__global__ __launch_bounds__(256) void select_scatter(const float* __restrict__ logits,
                                                      u64* __restrict__ keys) {
  int gid = blockIdx.x * 256 + threadIdx.x;  // 32768 = B*NB*E
  int b  = gid >> 14;
  int ne = gid & (NE_ - 1);

  float v0 = -1e30f, v1 = -1e30f, v2 = -1e30f;
  int   t0 = 0, t1 = 0, t2 = 0;

  const float* lg = logits + (size_t)b * HALF_;
  const u32 ib = (u32)b * HALF_ + (u32)ne;
  for (int t = 0; t < T_; ++t) {
    u32 i0 = (u32)t * (u32)NE_ + (u32)ne;
    float y = lg[i0] * noise_at(ib + (u32)t * (u32)NE_);
    if (y > v0)      { v2=v1; t2=t1; v1=v0; t1=t0; v0=y; t0=t; }
    else if (y > v1) { v2=v1; t2=t1; v1=y;  t1=t; }
    else if (y > v2) { v2=y;  t2=t; }
  }

  int n = ne >> 12;
  int e = ne & (E_ - 1);
  u64 klo = 0xFFFFFFFFull - (u32)e;
  atomicMax(&keys[((size_t)b * T_ + t0) * NB_ + n], ((u64)map_f32(v0) << 32) | klo);
  atomicMax(&keys[((size_t)b * T_ + t1) * NB_ + n], ((u64)map_f32(v1) << 32) | klo);
  atomicMax(&keys[((size_t)b * T_ + t2) * NB_ + n], ((u64)map_f32(v2) << 32) | klo);
}

// ---------------- Kernel 4: decode argmax -> idx + latent gather ----------------
__global__ __launch_bounds__(128) void finalize(const u64* __restrict__ keys,
                                                const float* __restrict__ W,
                                                float* __restrict__ out_idx,
                                                float* __restrict__ out_lat) {
  int slot = blockIdx.x;                     // (b*T+t)*NB + n
  int n = slot & (NB_ - 1);
  int e = (int)(0xFFFFFFFFu - (u32)keys[slot]) & (E_ - 1);
  if (threadIdx.x == 0) out_idx[slot] = (float)e;

  const float4 v = ((const float4*)(W + ((size_t)n * E_ + e) * D_))[threadIdx.x];
  ((float4*)(out_lat + (size_t)slot * D_))[threadIdx.x] = v;   // 128 x 16B = 2KB
}

// ---------------- Launch ----------------
extern "C" void kernel_launch(void* const* d_in, const int* in_sizes, int n_in,
                              void* d_out, int out_size, void* d_ws, size_t ws_size,
                              hipStream_t stream) {
  const float* x = (const float*)d_in[0];    // [B,T,NB*D] fp32
  const float* W = (const float*)d_in[1];    // [NB,E,D]  fp32

  float* out_idx    = (float*)d_out;                          // 32,768
  float* out_lat    = out_idx + (size_t)SLOTS_;               // 16,777,216
  float* out_logits = out_lat + (size_t)SLOTS_ * D_;          // 134,217,728

  // ws layout: keys | thr | xh | xl | wh | wl
  u64* keys = (u64*)d_ws;
  const size_t KEYS_B = (size_t)SLOTS_ * 8;                   // 256 KiB
  const size_t THR_B  = (size_t)SLOTS_ * 4;                   // 128 KiB
  const size_t XH_B   = (size_t)XN8_ * 16;                    // 32 MiB
  const size_t WH_B   = (size_t)WN8_ * 16;                    // 16 MiB
  bool split = ws_size >= KEYS_B + THR_B + 2 * XH_B + 2 * WH_B;

  u32*   thr = (u32*)((char*)d_ws + KEYS_B);
  char*  sp  = (char*)d_ws + KEYS_B + THR_B;
  f16x8* xh  = (f16x8*)sp;
  f16x8* xl  = (f16x8*)(sp + XH_B);
  f16x8* wh  = (f16x8*)(sp + 2 * XH_B);
  f16x8* wl  = (f16x8*)(sp + 2 * XH_B + WH_B);

  // tile-select records live in the out_lat region (overwritten by finalize later)
  u64* k0g = (u64*)out_lat;                                   // 8 MB each
  u64* k1g = k0g + RECN_;
  u64* k2g = k1g + RECN_;

  init_keys<<<SLOTS_ / 256, 256, 0, stream>>>(keys, thr);

  if (split) {
    presplit<<<(XN8_ + WN8_) / 256, 256, 0, stream>>>(x, W, xh, xl, wh, wl);
    gemm_presample<<<256, 256, 0, stream>>>(xh, xl, wh, wl, thr);
    gemm_fused<<<8192, 512, 0, stream>>>(xh, xl, wh, wl, out_logits, k0g, k1g, k2g, thr);
    merge_scatter2<<<SLOTS_ / 256, 256, 0, stream>>>(k0g, k1g, k2g, keys);
  } else {
    dim3 ggrid(E_ / BN, (B_ * T_) / BM, NB_);
    gemm_logits_fb<<<ggrid, 256, 0, stream>>>(x, W, out_logits);
    select_scatter<<<SLOTS_ / 256, 256, 0, stream>>>(out_logits, keys);
  }

  finalize<<<SLOTS_, 128, 0, stream>>>(keys, W, out_idx, out_lat);
}